// Round 12
// baseline (437.121 us; speedup 1.0000x reference)
//
#include <hip/hip_runtime.h>
#include <hip/hip_bf16.h>
#include <math.h>

// ---------------- problem constants ----------------
#define NN 98304            // nodes = B*S*G
#define CC 12               // node channels
#define EE 1572864          // edges (before self-loops)
#define ETOT (EE + NN)      // edges + self loops
#define BB 4
#define SS 512
#define DD 576              // d_model
#define HH 3
#define HDI 192
#define FFD 2048
#define MR (BB*SS)          // 2048 token rows
#define ND (NN*CC)
#define ATT_SCALE 0.07216878364870323f  // 1/sqrt(192)
#define NB 768              // sort buckets (128 nodes each)
#define BCAP 2560           // bucket capacity (mean 2176, +8 sigma)
#define BINB2 512           // binning blocks; 512*3264 == ETOT
#define CHUNK2 3264

typedef __hip_bfloat16 bf;
typedef __attribute__((ext_vector_type(8))) short s8v;
typedef __attribute__((ext_vector_type(4))) short s4v;
typedef __attribute__((ext_vector_type(4))) float f4v;

__device__ __forceinline__ void gl16(const void* g, void* l) {
    __builtin_amdgcn_global_load_lds(
        (const __attribute__((address_space(1))) unsigned int*)g,
        (__attribute__((address_space(3))) unsigned int*)l, 16, 0, 0);
}
__device__ __forceinline__ short bfbits(float f) {
    bf t = __float2bfloat16(f);
    return *(short*)&t;
}
__device__ __forceinline__ unsigned pk2(float a, float b) {
    return (unsigned)(unsigned short)bfbits(a) |
           ((unsigned)(unsigned short)bfbits(b) << 16);
}
__device__ __forceinline__ float lo16(unsigned v) { return __uint_as_float(v << 16); }
__device__ __forceinline__ float hi16(unsigned v) { return __uint_as_float(v & 0xffff0000u); }

// ---------------- GAT: node transform -> packed 32B rows ----------------
__global__ __launch_bounds__(256) void gat_node_k(
    const float* __restrict__ xin, const float* __restrict__ mask,
    const float* __restrict__ noise,
    const float* __restrict__ W, const float* __restrict__ a_s,
    const float* __restrict__ a_d,
    float4* __restrict__ rows, float* __restrict__ dval,
    int blend)
{
    int n = blockIdx.x * 256 + threadIdx.x;
    if (n >= NN) return;
    const float4* xr = (const float4*)(xin + (size_t)n*CC);
    float h[CC];
    float4 h0 = xr[0], h1 = xr[1], h2 = xr[2];
    h[0]=h0.x; h[1]=h0.y; h[2]=h0.z; h[3]=h0.w;
    h[4]=h1.x; h[5]=h1.y; h[6]=h1.z; h[7]=h1.w;
    h[8]=h2.x; h[9]=h2.y; h[10]=h2.z; h[11]=h2.w;
    if (blend) {
        const float4* mr = (const float4*)(mask  + (size_t)n*CC);
        const float4* nr = (const float4*)(noise + (size_t)n*CC);
        float m[CC], z[CC];
        float4 m0=mr[0],m1=mr[1],m2=mr[2], z0=nr[0],z1=nr[1],z2=nr[2];
        m[0]=m0.x;m[1]=m0.y;m[2]=m0.z;m[3]=m0.w;m[4]=m1.x;m[5]=m1.y;m[6]=m1.z;m[7]=m1.w;
        m[8]=m2.x;m[9]=m2.y;m[10]=m2.z;m[11]=m2.w;
        z[0]=z0.x;z[1]=z0.y;z[2]=z0.z;z[3]=z0.w;z[4]=z1.x;z[5]=z1.y;z[6]=z1.z;z[7]=z1.w;
        z[8]=z2.x;z[9]=z2.y;z[10]=z2.z;z[11]=z2.w;
#pragma unroll
        for (int c = 0; c < CC; ++c) h[c] = h[c]*m[c] + z[c]*(1.0f-m[c]);
    }
    float sv = 0.f, dv = 0.f;
    float o[CC];
#pragma unroll
    for (int oc = 0; oc < CC; ++oc) {
        float a = 0.f;
#pragma unroll
        for (int ic = 0; ic < CC; ++ic) a += h[ic]*W[oc*CC+ic];
        o[oc] = a;
        sv += a * a_s[oc]; dv += a * a_d[oc];
    }
    float4 r0, r1;
    r0.x = sv;
    r0.y = __uint_as_float(pk2(o[0], o[1]));
    r0.z = __uint_as_float(pk2(o[2], o[3]));
    r0.w = __uint_as_float(pk2(o[4], o[5]));
    r1.x = __uint_as_float(pk2(o[6], o[7]));
    r1.y = __uint_as_float(pk2(o[8], o[9]));
    r1.z = __uint_as_float(pk2(o[10], o[11]));
    r1.w = 0.f;
    rows[(size_t)n*2]   = r0;
    rows[(size_t)n*2+1] = r1;
    dval[n] = dv;
}

// ---------------- atomic-free hierarchical binning (3 phases) -------------
__global__ __launch_bounds__(256) void binA1_k(
    const int* __restrict__ e1, int* __restrict__ gcnt)
{
    __shared__ int lh[NB];
    const int tid = threadIdx.x;
    const int lo = blockIdx.x * CHUNK2, hi = lo + CHUNK2;
    for (int b = tid; b < NB; b += 256) lh[b] = 0;
    __syncthreads();
    for (int i = lo + tid; i < hi; i += 256) {
        int d = (i < EE) ? e1[i] : (i - EE);
        atomicAdd(&lh[d >> 7], 1);
    }
    __syncthreads();
    for (int b = tid; b < NB; b += 256)
        gcnt[(size_t)blockIdx.x*NB + b] = lh[b];
}

__global__ __launch_bounds__(512) void binscan_k(
    const int* __restrict__ gcnt, int* __restrict__ gbase, int* __restrict__ bcnt)
{
    __shared__ int sh[BINB2];
    const int b = blockIdx.x, t = threadIdx.x;
    int v = gcnt[(size_t)t*NB + b];
    sh[t] = v; __syncthreads();
    for (int off = 1; off < BINB2; off <<= 1) {
        int add = (t >= off) ? sh[t-off] : 0;
        __syncthreads();
        sh[t] += add;
        __syncthreads();
    }
    gbase[(size_t)b*BINB2 + t] = sh[t] - v;
    if (t == BINB2-1) bcnt[b] = sh[BINB2-1];
}

__global__ __launch_bounds__(256) void binA2_k(
    const int* __restrict__ e0, const int* __restrict__ e1,
    const int* __restrict__ gbase, unsigned* __restrict__ pairs)
{
    __shared__ int lbase[NB];
    __shared__ int lh[NB];
    const int tid = threadIdx.x;
    const int lo = blockIdx.x * CHUNK2, hi = lo + CHUNK2;
    for (int b = tid; b < NB; b += 256) {
        lbase[b] = gbase[(size_t)b*BINB2 + blockIdx.x];
        lh[b] = 0;
    }
    __syncthreads();
    for (int i = lo + tid; i < hi; i += 256) {
        int s, d;
        if (i < EE) { s = e0[i]; d = e1[i]; }
        else        { s = i - EE; d = s; }
        int b = d >> 7;
        int p = lbase[b] + atomicAdd(&lh[b], 1);
        if (p < BCAP)
            pairs[(size_t)b*BCAP + p] = ((unsigned)(d & 127) << 17) | (unsigned)s;
    }
}

// ---------------- per-bucket fine counting sort, IN PLACE ----------------
__global__ __launch_bounds__(1024) void binB_k(
    unsigned* __restrict__ pairs, const int* __restrict__ bcnt,
    int* __restrict__ cnt, int* __restrict__ offs)
{
    __shared__ unsigned ent[BCAP];
    __shared__ int lh[128], ls[128], lc[128];
    const int b = blockIdx.x, tid = threadIdx.x;
    const int n = min(bcnt[b], BCAP);
    for (int i = tid; i < n; i += 1024) ent[i] = pairs[(size_t)b*BCAP + i];
    if (tid < 128) lh[tid] = 0;
    __syncthreads();
    for (int i = tid; i < n; i += 1024) atomicAdd(&lh[ent[i] >> 17], 1);
    __syncthreads();
    if (tid == 0) { int run = 0; for (int j = 0; j < 128; ++j) { ls[j] = run; run += lh[j]; } }
    __syncthreads();
    if (tid < 128) {
        int node = b*128 + tid;
        cnt[node]  = lh[tid];
        offs[node] = b*BCAP + ls[tid];
        lc[tid]    = ls[tid];
    }
    __syncthreads();
    for (int i = tid; i < n; i += 1024) {
        unsigned v = ent[i];
        int dl = (int)(v >> 17);
        int p = atomicAdd(&lc[dl], 1);
        pairs[(size_t)b*BCAP + p] = v & 0x1FFFFu;
    }
}

// ---------------- GAT aggregation: 8 lanes/node, shfl reduce, NO atomics ---
__global__ __launch_bounds__(256) void gat_agg8_k(
    const unsigned* __restrict__ pairs, const int* __restrict__ cnt,
    const int* __restrict__ offs,
    const float4* __restrict__ rows, const float* __restrict__ dval,
    const float* __restrict__ bias,
    float* __restrict__ out, bf* __restrict__ outb, int dotanh)
{
    int g = blockIdx.x*32 + (threadIdx.x >> 3);
    int l = threadIdx.x & 7;
    if (g >= NN) return;
    int beg = offs[g], m = cnt[g];
    float dv = dval[g];
    float acc[CC] = {};
    float den = 0.f;
    for (int i = l; i < m; i += 8) {
        unsigned s = pairs[beg + i];
        float4 r0 = rows[(size_t)s*2];
        float4 r1 = rows[(size_t)s*2+1];
        float e = r0.x + dv;
        e = e > 0.f ? e : 0.2f*e;
        float w = __expf(e);
        den += w;
        unsigned p01 = __float_as_uint(r0.y), p23 = __float_as_uint(r0.z);
        unsigned p45 = __float_as_uint(r0.w), p67 = __float_as_uint(r1.x);
        unsigned p89 = __float_as_uint(r1.y), pab = __float_as_uint(r1.z);
        acc[0]  += w*lo16(p01); acc[1]  += w*hi16(p01);
        acc[2]  += w*lo16(p23); acc[3]  += w*hi16(p23);
        acc[4]  += w*lo16(p45); acc[5]  += w*hi16(p45);
        acc[6]  += w*lo16(p67); acc[7]  += w*hi16(p67);
        acc[8]  += w*lo16(p89); acc[9]  += w*hi16(p89);
        acc[10] += w*lo16(pab); acc[11] += w*hi16(pab);
    }
#pragma unroll
    for (int off = 1; off < 8; off <<= 1) {
        den += __shfl_xor(den, off);
#pragma unroll
        for (int c = 0; c < CC; ++c) acc[c] += __shfl_xor(acc[c], off);
    }
    if (l == 0) {
        float inv = 1.f / den;
        float r[CC];
#pragma unroll
        for (int c = 0; c < CC; ++c) {
            r[c] = acc[c]*inv + bias[c];
            if (dotanh) r[c] = tanhf(r[c]);
        }
        if (out) {
            float4* orow = (float4*)(out + (size_t)g*CC);
            orow[0] = make_float4(r[0],r[1],r[2],r[3]);
            orow[1] = make_float4(r[4],r[5],r[6],r[7]);
            orow[2] = make_float4(r[8],r[9],r[10],r[11]);
        }
        if (outb) {
            s4v* brow = (s4v*)(outb + (size_t)g*CC);
            s4v b0, b1, b2;
            b0[0]=bfbits(r[0]); b0[1]=bfbits(r[1]); b0[2]=bfbits(r[2]); b0[3]=bfbits(r[3]);
            b1[0]=bfbits(r[4]); b1[1]=bfbits(r[5]); b1[2]=bfbits(r[6]); b1[3]=bfbits(r[7]);
            b2[0]=bfbits(r[8]); b2[1]=bfbits(r[9]); b2[2]=bfbits(r[10]); b2[3]=bfbits(r[11]);
            brow[0]=b0; brow[1]=b1; brow[2]=b2;
        }
    }
}

// ---------------- bf16 MFMA NT GEMM (LDS-swizzled, TBM in {32,64,128}) ----
// vtmode: batch z1==2 writes Cb in transposed V layout [bh][d][s] (QKV fusion)
template<int TBM>
__global__ __launch_bounds__(256) void gemm_bt(
    const bf* __restrict__ A, const bf* __restrict__ B,
    const float* __restrict__ bias, float* __restrict__ Cf, bf* __restrict__ Cb,
    int K, int lda, int ldb, int ldc,
    long long sA1, long long sA2, long long sB1, long long sB2,
    long long sC1, long long sC2, int bdiv, long long sBias,
    float scale, int relu, int vtmode)
{
    constexpr int MI = TBM/32;
    __shared__ bf As[TBM*32];
    __shared__ bf Bs[64*32];
    const int tid = threadIdx.x, lane = tid & 63, wave = tid >> 6;
    const int z = blockIdx.z, z1 = z / bdiv, z2 = z % bdiv;
    const bf* Ab = A + z1*sA1 + z2*sA2;
    const bf* Bb = B + z1*sB1 + z2*sB2;
    const int bm = blockIdx.y * TBM, bn = blockIdx.x * 64;
    const int l4 = lane >> 2;
    const int swz0 = (l4 >> 1) & 3;
    const int lc = (((lane & 3) ^ swz0) * 8);
    const int arow0 = wave*((TBM==128)?32:16) + l4;
    const int brow  = wave*16 + l4;
    const int wm = wave >> 1, wn = wave & 1;
    const int fr = lane & 15;
    const int gsw = (((lane >> 4) ^ ((fr >> 1) & 3)) * 8);
    f4v acc[MI][2] = {};

    for (int k0 = 0; k0 < K; k0 += 32) {
        if constexpr (TBM == 32) {
            if (wave < 2)
                gl16(Ab + (size_t)(bm + arow0)*lda + k0 + lc, As + wave*512);
        } else if constexpr (TBM == 64) {
            gl16(Ab + (size_t)(bm + arow0)*lda + k0 + lc, As + wave*512);
        } else {
            gl16(Ab + (size_t)(bm + arow0)*lda + k0 + lc, As + wave*1024);
            gl16(Ab + (size_t)(bm + arow0 + 16)*lda + k0 + lc, As + wave*1024 + 512);
        }
        gl16(Bb + (size_t)(bn + brow )*ldb + k0 + lc, Bs + wave*512);
        __syncthreads();
        s8v af[MI], bfv[2];
#pragma unroll
        for (int mi = 0; mi < MI; ++mi)
            af[mi] = *(const s8v*)&As[(wm*(TBM/2) + mi*16 + fr)*32 + gsw];
#pragma unroll
        for (int nj = 0; nj < 2; ++nj)
            bfv[nj] = *(const s8v*)&Bs[(wn*32 + nj*16 + fr)*32 + gsw];
#pragma unroll
        for (int mi = 0; mi < MI; ++mi)
#pragma unroll
            for (int nj = 0; nj < 2; ++nj)
                acc[mi][nj] = __builtin_amdgcn_mfma_f32_16x16x32_bf16(
                    af[mi], bfv[nj], acc[mi][nj], 0, 0, 0);
        __syncthreads();
    }

    const float* bp = bias ? bias + z1*sBias : nullptr;
    if (vtmode && z1 == 2) {
        bf* vt = Cb + 2*sC1;
#pragma unroll
        for (int mi = 0; mi < MI; ++mi) {
#pragma unroll
            for (int nj = 0; nj < 2; ++nj) {
                int col = bn + wn*32 + nj*16 + fr;
                float bv = bp ? bp[col] : 0.f;
                int row0 = bm + wm*(TBM/2) + mi*16 + (lane>>4)*4;
                int b = row0 >> 9, s0 = row0 & 511;
                int h = col / HDI, dd = col - h*HDI;
                s4v pk;
#pragma unroll
                for (int r = 0; r < 4; ++r)
                    pk[r] = bfbits(acc[mi][nj][r] + bv);
                *(s4v*)&vt[((size_t)((b*HH + h)*HDI + dd))*SS + s0] = pk;
            }
        }
        return;
    }
    float* Cfb = Cf ? Cf + z1*sC1 + z2*sC2 : nullptr;
    bf*    Cbb = Cb ? Cb + z1*sC1 + z2*sC2 : nullptr;
#pragma unroll
    for (int mi = 0; mi < MI; ++mi) {
#pragma unroll
        for (int nj = 0; nj < 2; ++nj) {
            int col = bn + wn*32 + nj*16 + fr;
            float bv = bp ? bp[col] : 0.f;
#pragma unroll
            for (int r = 0; r < 4; ++r) {
                int row = bm + wm*(TBM/2) + mi*16 + (lane>>4)*4 + r;
                float vv = (acc[mi][nj][r] + bv) * scale;
                if (relu) vv = fmaxf(vv, 0.f);
                if (Cfb) Cfb[(size_t)row*ldc + col] = vv;
                if (Cbb) Cbb[(size_t)row*ldc + col] = __float2bfloat16(vv);
            }
        }
    }
}

// ---------------- direct conv GEMM, 32x64 tile, single pass, fused epi ----
// A logical: [M=B*Lout][K=3*CIN] from padded activations [B][Lin+2][CIN].
// MODE 0: s1p1 row=l+kk; 1: s2 p(0,1) row=2l+kk+1; 2: up x2 row=(l+kk+1)>>1;
// MODE 3: concat(A0,A1) halves s1p1.
template<int CIN, int MODE>
__global__ __launch_bounds__(256) void conv32_k(
    const bf* __restrict__ A0, const bf* __restrict__ A1,
    const bf* __restrict__ Bw, const float* __restrict__ bias,
    bf* __restrict__ outb, float* __restrict__ outf,
    int K, int N, int Lout, int Lin, int relu)
{
    __shared__ bf As[32*32];
    __shared__ bf Bs[64*32];
    const int tid = threadIdx.x, lane = tid & 63, wave = tid >> 6;
    const int bm = blockIdx.y * 32, bn = blockIdx.x * 64;
    const int l4 = lane >> 2;
    const int swz0 = (l4 >> 1) & 3;
    const int lc = (((lane & 3) ^ swz0) * 8);
    const int arow = bm + wave*16 + l4;          // used by waves 0,1
    const int brow = bn + wave*16 + l4;
    const int ab = arow / Lout, al = arow % Lout;
    const int wm = wave >> 1, wn = wave & 1;
    const int fr = lane & 15;
    const int gsw = (((lane >> 4) ^ ((fr >> 1) & 3)) * 8);
    f4v acc[2] = {};

    for (int k0 = 0; k0 < K; k0 += 32) {
        int kk  = k0 / CIN;
        int ci0 = k0 - kk*CIN;
        if (wave < 2) {
            int row;
            if constexpr (MODE == 1)      row = 2*al + kk + 1;
            else if constexpr (MODE == 2) row = (al + kk + 1) >> 1;
            else                          row = al + kk;
            const bf* src;
            if constexpr (MODE == 3) {
                constexpr int CH = CIN/2;
                bool lohalf = ci0 < CH;
                src = (lohalf ? A0 : A1)
                    + ((size_t)(ab*(Lin+2) + row))*CH + (lohalf ? ci0 : ci0 - CH);
            } else {
                src = A0 + ((size_t)(ab*(Lin+2) + row))*CIN + ci0;
            }
            gl16(src + lc, As + wave*512);
        }
        gl16(Bw + (size_t)brow*K + k0 + lc, Bs + wave*512);
        __syncthreads();
        s8v af = *(const s8v*)&As[(wm*16 + fr)*32 + gsw];
        s8v b0 = *(const s8v*)&Bs[(wn*32 + fr)*32 + gsw];
        s8v b1 = *(const s8v*)&Bs[(wn*32 + 16 + fr)*32 + gsw];
        acc[0] = __builtin_amdgcn_mfma_f32_16x16x32_bf16(af, b0, acc[0], 0, 0, 0);
        acc[1] = __builtin_amdgcn_mfma_f32_16x16x32_bf16(af, b1, acc[1], 0, 0, 0);
        __syncthreads();
    }

#pragma unroll
    for (int nj = 0; nj < 2; ++nj) {
        int col = bn + wn*32 + nj*16 + fr;
        float bv = bias[col];
#pragma unroll
        for (int r = 0; r < 4; ++r) {
            int row = bm + wm*16 + (lane>>4)*4 + r;
            float vv = acc[nj][r] + bv;
            if (relu) vv = fmaxf(vv, 0.f);
            if (outb) {
                int b = row / Lout, l = row % Lout;
                outb[((size_t)(b*(Lout+2) + l + 1))*N + col] = __float2bfloat16(vv);
            }
            if (outf) outf[(size_t)row*N + col] = vv;
        }
    }
}

// ---------------- unified prep: casts + bias packs + pad-zeros ------------
struct PJob { int type; const float* src; void* dst; int a; int b; };
struct PJobs { PJob j[14]; };
__global__ __launch_bounds__(256) void prep_k(PJobs J)
{
    PJob jb = J.j[blockIdx.y];
    if (jb.type == 0) {
        for (int i = blockIdx.x*256 + threadIdx.x; i < jb.a; i += gridDim.x*256) {
            float4 v = ((const float4*)jb.src)[i];
            s4v p;
            p[0]=bfbits(v.x); p[1]=bfbits(v.y); p[2]=bfbits(v.z); p[3]=bfbits(v.w);
            ((s4v*)jb.dst)[i] = p;
        }
    } else if (jb.type == 1) {
        for (int i = blockIdx.x*256 + threadIdx.x; i < jb.a; i += gridDim.x*256)
            ((float4*)jb.dst)[i] = ((const float4*)jb.src)[i];
    } else {
        int n8 = BB * 2 * (jb.b >> 3);
        for (int i = blockIdx.x*256 + threadIdx.x; i < n8; i += gridDim.x*256) {
            int c8 = i % (jb.b >> 3); int r = i / (jb.b >> 3);
            int bb = r >> 1; int row = (r & 1) ? (jb.a + 1) : 0;
            s8v z = {0,0,0,0,0,0,0,0};
            *(s8v*)&((bf*)jb.dst)[((size_t)(bb*(jb.a+2) + row))*jb.b + c8*8] = z;
        }
    }
}

// ---------------- 5-job conv weight transpose -----------------------------
struct WJob { const float* w; bf* wT; int Cout; int Cin; };
struct WJobs { WJob j[5]; };
__global__ __launch_bounds__(256) void wtrans5_k(WJobs J)
{
    WJob jb = J.j[blockIdx.y];
    int n8 = jb.Cout * 3 * (jb.Cin >> 3);
    for (int i = blockIdx.x*256 + threadIdx.x; i < n8; i += gridDim.x*256) {
        int c8 = i % (jb.Cin >> 3); int r = i / (jb.Cin >> 3);
        int kk = r % 3; int co = r / 3;
        int ci = c8 * 8;
        s8v ov;
#pragma unroll
        for (int j = 0; j < 8; ++j)
            ov[j] = bfbits(jb.w[((size_t)co*jb.Cin + ci + j)*3 + kk]);
        *(s8v*)&jb.wT[(size_t)co*3*jb.Cin + (size_t)kk*jb.Cin + ci] = ov;
    }
}

// ---------------- softmax rows of 512, f32 -> bf16 ----------------
__global__ __launch_bounds__(256) void softmax_k(
    const float* __restrict__ S, bf* __restrict__ P)
{
    int row = blockIdx.x; size_t base = (size_t)row * SS;
    int tid = threadIdx.x;
    __shared__ float red[256];
    float v0 = S[base+tid], v1 = S[base+tid+256];
    red[tid] = fmaxf(v0, v1); __syncthreads();
    for (int off = 128; off > 0; off >>= 1) {
        if (tid < off) red[tid] = fmaxf(red[tid], red[tid+off]);
        __syncthreads();
    }
    float mx = red[0]; __syncthreads();
    float e0 = __expf(v0-mx), e1 = __expf(v1-mx);
    red[tid] = e0+e1; __syncthreads();
    for (int off = 128; off > 0; off >>= 1) {
        if (tid < off) red[tid] += red[tid+off];
        __syncthreads();
    }
    float inv = 1.f / red[0];
    P[base+tid]     = __float2bfloat16(e0*inv);
    P[base+tid+256] = __float2bfloat16(e1*inv);
}

// ---------------- layernorm over D=576 (ob optionally padded-layout) ------
__global__ __launch_bounds__(256) void ln_k(
    const float* __restrict__ a, const float* __restrict__ r,
    const float* __restrict__ g, const float* __restrict__ be,
    float* __restrict__ out, bf* __restrict__ ob, int padout)
{
    int row = blockIdx.x; int tid = threadIdx.x;
    __shared__ float red[256], red2[256];
    size_t base = (size_t)row * DD;
    size_t base2 = padout ? ((size_t)(row + 2*(row/SS) + 1))*DD : base;
    float x0 = a[base+tid]      + r[base+tid];
    float x1 = a[base+tid+256]  + r[base+tid+256];
    float x2 = (tid < 64) ? (a[base+tid+512] + r[base+tid+512]) : 0.f;
    float s  = x0+x1+x2;
    float s2 = x0*x0 + x1*x1 + x2*x2;
    red[tid] = s; red2[tid] = s2; __syncthreads();
    for (int off = 128; off > 0; off >>= 1) {
        if (tid < off) { red[tid] += red[tid+off]; red2[tid] += red2[tid+off]; }
        __syncthreads();
    }
    float mean = red[0] / (float)DD;
    float var  = red2[0] / (float)DD - mean*mean;
    float inv = rsqrtf(var + 1e-5f);
    float y0 = (x0-mean)*inv*g[tid]     + be[tid];
    float y1 = (x1-mean)*inv*g[tid+256] + be[tid+256];
    if (out) { out[base+tid] = y0; out[base+tid+256] = y1; }
    if (ob)  { ob[base2+tid] = __float2bfloat16(y0); ob[base2+tid+256] = __float2bfloat16(y1); }
    if (tid < 64) {
        float y2 = (x2-mean)*inv*g[tid+512] + be[tid+512];
        if (out) out[base+tid+512] = y2;
        if (ob)  ob[base2+tid+512] = __float2bfloat16(y2);
    }
}

// ---------------- launch ----------------
extern "C" void kernel_launch(void* const* d_in, const int* in_sizes, int n_in,
                              void* d_out, int out_size, void* d_ws, size_t ws_size,
                              hipStream_t stream)
{
    const int*   edge   = (const int*)  d_in[0];
    const float* x      = (const float*)d_in[1];
    const float* mask   = (const float*)d_in[2];
    const float* noise  = (const float*)d_in[3];
    const float* W_enc  = (const float*)d_in[4];
    const float* asrc_e = (const float*)d_in[5];
    const float* adst_e = (const float*)d_in[6];
    const float* b_enc  = (const float*)d_in[7];
    const float* Wq = (const float*)d_in[8];  const float* bq = (const float*)d_in[9];
    const float* Wk = (const float*)d_in[10]; const float* bk = (const float*)d_in[11];
    const float* Wv = (const float*)d_in[12]; const float* bv = (const float*)d_in[13];
    const float* Wo = (const float*)d_in[14]; const float* bo = (const float*)d_in[15];
    const float* ln1g = (const float*)d_in[16]; const float* ln1b = (const float*)d_in[17];
    const float* W1 = (const float*)d_in[18]; const float* b1 = (const float*)d_in[19];
    const float* W2 = (const float*)d_in[20]; const float* b2 = (const float*)d_in[21];
    const float* ln2g = (const float*)d_in[22]; const float* ln2b = (const float*)d_in[23];
    const float* enc1_w = (const float*)d_in[24]; const float* enc1_b = (const float*)d_in[25];
    const float* down_w = (const float*)d_in[26]; const float* down_b = (const float*)d_in[27];
    const float* bott_w = (const float*)d_in[28]; const float* bott_b = (const float*)d_in[29];
    const float* up_w   = (const float*)d_in[30]; const float* up_b   = (const float*)d_in[31];
    const float* dec_w  = (const float*)d_in[32]; const float* dec_b  = (const float*)d_in[33];
    const float* W_dec  = (const float*)d_in[34];
    const float* asrc_d = (const float*)d_in[35];
    const float* adst_d = (const float*)d_in[36];
    const float* b_dec  = (const float*)d_in[37];
    float* out = (float*)d_out;

    float* ws = (float*)d_ws;
    // float-unit offsets; total 23,632,320 floats = 94.5 MB
    float4*   rows  = (float4*)ws;              // 786432 f
    float*    dval  = ws + 786432;              // 98304
    int*      cnt   = (int*)(ws + 884736);      // 98304
    int*      offs  = (int*)(ws + 983040);      // 98304
    unsigned* pairs = (unsigned*)(ws + 1376256);// 1966080 u32
    int*      bcnt  = (int*)(ws + 3342336);     // 1024
    float*    t     = ws + 3343360;             // 1179648
    bf*       tb    = (bf*)(ws + 4523008);      // 589824 f
    bf*       qb    = (bf*)(ws + 5112832);      // 589824 f
    bf*       kb    = (bf*)(ws + 5702656);      // 589824 f
    bf*       vb    = (bf*)(ws + 6292480);      // 589824 f (holds V TRANSPOSED)
    float*    big   = ws + 6882304;             // 4718592 f shared scratch
    int*      gcnt  = (int*)big;                // sort: 393216
    int*      gbase = (int*)(big + 393216);     // sort: 393216
    float*    scores = big;                     // attn: 3145728 f
    bf*       Pb    = (bf*)(big + 3145728);     // attn: 1572864 f
    bf*       wTbott = (bf*)big;                // conv: 1990656 f
    float*    o     = ws + 11600896;            // 1179648
    float*    t1    = ws + 12780544;            // 1179648
    bf*       t1b   = (bf*)(ws + 13960192);     // 589824 f
    bf*       ff1b  = (bf*)(ws + 14550016);     // 2097152 f
    bf*       t2p   = (bf*)(ws + 16647168);     // 592128 f  [4][514][576]
    bf*       e1p   = (bf*)(ws + 17239296);     // 592128 f  [4][514][576]
    bf*       d1p   = (bf*)(ws + 17831424);     // 594432 f  [4][258][1152]
    bf*       btbp  = (bf*)(ws + 18425856);     // 594432 f  [4][258][1152]
    bf*       upp   = (bf*)(ws + 19020288);     // 592128 f  [4][514][576]
    float*    dec   = ws + 19612416;            // 1179648
    bf*       wTb   = (bf*)(ws + 20792064);     // 995328 f
    bf*       Wqb   = (bf*)(ws + 21787392);     // 165888 f each
    bf*       Wkb   = (bf*)(ws + 21953280);
    bf*       Wvb   = (bf*)(ws + 22119168);
    bf*       Wob   = (bf*)(ws + 22285056);
    bf*       W1b   = (bf*)(ws + 22450944);     // 589824
    bf*       W2b   = (bf*)(ws + 23040768);     // 589824
    float*    biasQKV = ws + 23630592;          // 1728, end 23632320
    bf*       vt    = vb;                       // V written transposed by QKV GEMM
    bf*       attnO = qb;                       // alias: qb dead after scores GEMM
    // conv wT homes (all dead by conv phase):
    bf*       wTenc  = wTb;                     // 497664 f needed
    bf*       wTdown = (bf*)t;                  // t dead after ln1
    bf*       wTup   = kb;                      // kb(+vb) dead after PV
    bf*       wTdec  = tb;                      // tb(+qb) dead after Wo

    const int* e0 = edge;
    const int* e1i = edge + EE;

    // ---- 0. atomic-free binning + in-place fine sort ----
    binA1_k<<<BINB2, 256, 0, stream>>>(e1i, gcnt);
    binscan_k<<<NB, BINB2, 0, stream>>>(gcnt, gbase, bcnt);
    binA2_k<<<BINB2, 256, 0, stream>>>(e0, e1i, gbase, pairs);
    binB_k<<<NB, 1024, 0, stream>>>(pairs, bcnt, cnt, offs);

    // ---- unified prep ----
    {
        PJobs J;
        J.j[0]  = { 0, Wq, Wqb, DD*DD/4, 0 };
        J.j[1]  = { 0, Wk, Wkb, DD*DD/4, 0 };
        J.j[2]  = { 0, Wv, Wvb, DD*DD/4, 0 };
        J.j[3]  = { 0, Wo, Wob, DD*DD/4, 0 };
        J.j[4]  = { 0, W1, W1b, FFD*DD/4, 0 };
        J.j[5]  = { 0, W2, W2b, FFD*DD/4, 0 };
        J.j[6]  = { 1, bq, biasQKV,        DD/4, 0 };
        J.j[7]  = { 1, bk, biasQKV + DD,   DD/4, 0 };
        J.j[8]  = { 1, bv, biasQKV + 2*DD, DD/4, 0 };
        J.j[9]  = { 2, nullptr, t2p,  512, 576 };
        J.j[10] = { 2, nullptr, e1p,  512, 576 };
        J.j[11] = { 2, nullptr, d1p,  256, 1152 };
        J.j[12] = { 2, nullptr, btbp, 256, 1152 };
        J.j[13] = { 2, nullptr, upp,  512, 576 };
        prep_k<<<dim3(576, 14), 256, 0, stream>>>(J);
    }

    // ---- 1. GAT encoder ----
    gat_node_k<<<NN/256, 256, 0, stream>>>(x, mask, noise, W_enc, asrc_e, adst_e,
                                           rows, dval, 1);
    gat_agg8_k<<<NN/32, 256, 0, stream>>>(pairs, cnt, offs, rows, dval, b_enc,
                                          t, tb, 0);

    // ---- 2. transformer layer ----
    gemm_bt<128><<<dim3(9,16,3), 256, 0, stream>>>(tb, Wqb, biasQKV, nullptr, qb,
        DD, DD, DD, DD,
        0,0, (long long)DD*DD,0, (long long)MR*DD,0, 1, DD, 1.f, 0, 1);
    gemm_bt<128><<<dim3(8,4,12), 256, 0, stream>>>(qb, kb, nullptr, scores, nullptr,
        HDI, DD, DD, SS,
        (long long)SS*DD, HDI, (long long)SS*DD, HDI,
        3LL*SS*SS, (long long)SS*SS, HH, 0, ATT_SCALE, 0, 0);
    softmax_k<<<12*SS, 256, 0, stream>>>(scores, Pb);
    gemm_bt<32><<<dim3(3,16,12), 256, 0, stream>>>(Pb, vt, nullptr, nullptr, attnO,
        SS, SS, SS, DD,
        3LL*SS*SS, (long long)SS*SS, 3LL*HDI*SS, (long long)HDI*SS,
        (long long)SS*DD, HDI, HH, 0, 1.f, 0, 0);
    gemm_bt<32><<<dim3(9,64,1), 256, 0, stream>>>(attnO, Wob, bo, o, nullptr,
        DD, DD, DD, DD, 0,0,0,0,0,0, 1, 0, 1.f, 0, 0);
    ln_k<<<MR, 256, 0, stream>>>(t, o, ln1g, ln1b, t1, t1b, 0);
    gemm_bt<128><<<dim3(32,16,1), 256, 0, stream>>>(t1b, W1b, b1, nullptr, ff1b,
        DD, DD, DD, FFD, 0,0,0,0,0,0, 1, 0, 1.f, 1, 0);
    gemm_bt<32><<<dim3(9,64,1), 256, 0, stream>>>(ff1b, W2b, b2, o, nullptr,
        FFD, FFD, FFD, DD, 0,0,0,0,0,0, 1, 0, 1.f, 0, 0);
    ln_k<<<MR, 256, 0, stream>>>(t1, o, ln2g, ln2b, nullptr, t2p, 1);

    // ---- 3. UNet1d: batched weight-transpose, then single-pass conv GEMMs --
    {
        WJobs W5;
        W5.j[0] = { enc1_w, wTenc,  576,  576 };
        W5.j[1] = { down_w, wTdown, 1152, 576 };
        W5.j[2] = { bott_w, wTbott, 1152, 1152 };
        W5.j[3] = { up_w,   wTup,   576,  1152 };
        W5.j[4] = { dec_w,  wTdec,  576,  1152 };
        wtrans5_k<<<dim3(1024, 5), 256, 0, stream>>>(W5);
    }
    // enc1: 576->576, L=512, s1p1
    conv32_k<576,0><<<dim3(9,64), 256, 0, stream>>>(t2p, nullptr, wTenc, enc1_b,
        e1p, nullptr, 1728, 576, 512, 512, 1);
    // down: 576->1152, stride2 pad(0,1)
    conv32_k<576,1><<<dim3(18,32), 256, 0, stream>>>(e1p, nullptr, wTdown, down_b,
        d1p, nullptr, 1728, 1152, 256, 512, 1);
    // bott: 1152->1152, L=256, s1p1
    conv32_k<1152,0><<<dim3(18,32), 256, 0, stream>>>(d1p, nullptr, wTbott, bott_b,
        btbp, nullptr, 3456, 1152, 256, 256, 1);
    // up: repeat x2 then 1152->576, L=512
    conv32_k<1152,2><<<dim3(9,64), 256, 0, stream>>>(btbp, nullptr, wTup, up_b,
        upp, nullptr, 3456, 576, 512, 256, 1);
    // dec: concat(up, e1) 1152->576, L=512, no relu, f32 out
    conv32_k<1152,3><<<dim3(9,64), 256, 0, stream>>>(upp, e1p, wTdec, dec_b,
        nullptr, dec, 3456, 576, 512, 512, 0);

    // ---- 4. GAT decoder + tanh ----
    gat_node_k<<<NN/256, 256, 0, stream>>>(dec, nullptr, nullptr, W_dec, asrc_d, adst_d,
                                           rows, dval, 0);
    gat_agg8_k<<<NN/32, 256, 0, stream>>>(pairs, cnt, offs, rows, dval, b_dec,
                                          out, nullptr, 1);
}

// Round 13
// 358.757 us; speedup vs baseline: 1.2184x; 1.2184x over previous
//
#include <hip/hip_runtime.h>
#include <hip/hip_bf16.h>
#include <math.h>

// ---------------- problem constants ----------------
#define NN 98304
#define CC 12
#define EE 1572864
#define ETOT (EE + NN)
#define BB 4
#define SS 512
#define DD 576
#define HH 3
#define HDI 192
#define FFD 2048
#define MR (BB*SS)
#define ND (NN*CC)
#define ATT_SCALE 0.07216878364870323f
#define NB 768
#define BCAP 2560
#define BINB2 512
#define CHUNK2 3264

typedef __hip_bfloat16 bf;
typedef __attribute__((ext_vector_type(8))) short s8v;
typedef __attribute__((ext_vector_type(4))) short s4v;
typedef __attribute__((ext_vector_type(4))) float f4v;

__device__ __forceinline__ void gl16(const void* g, void* l) {
    __builtin_amdgcn_global_load_lds(
        (const __attribute__((address_space(1))) unsigned int*)g,
        (__attribute__((address_space(3))) unsigned int*)l, 16, 0, 0);
}
__device__ __forceinline__ short bfbits(float f) {
    bf t = __float2bfloat16(f);
    return *(short*)&t;
}
__device__ __forceinline__ unsigned pk2(float a, float b) {
    return (unsigned)(unsigned short)bfbits(a) |
           ((unsigned)(unsigned short)bfbits(b) << 16);
}
__device__ __forceinline__ float lo16(unsigned v) { return __uint_as_float(v << 16); }
__device__ __forceinline__ float hi16(unsigned v) { return __uint_as_float(v & 0xffff0000u); }

// ---------------- GAT: node transform -> packed 32B rows ----------------
__global__ __launch_bounds__(256) void gat_node_k(
    const float* __restrict__ xin, const float* __restrict__ mask,
    const float* __restrict__ noise,
    const float* __restrict__ W, const float* __restrict__ a_s,
    const float* __restrict__ a_d,
    float4* __restrict__ rows, float* __restrict__ dval,
    int blend)
{
    int n = blockIdx.x * 256 + threadIdx.x;
    if (n >= NN) return;
    const float4* xr = (const float4*)(xin + (size_t)n*CC);
    float h[CC];
    float4 h0 = xr[0], h1 = xr[1], h2 = xr[2];
    h[0]=h0.x; h[1]=h0.y; h[2]=h0.z; h[3]=h0.w;
    h[4]=h1.x; h[5]=h1.y; h[6]=h1.z; h[7]=h1.w;
    h[8]=h2.x; h[9]=h2.y; h[10]=h2.z; h[11]=h2.w;
    if (blend) {
        const float4* mr = (const float4*)(mask  + (size_t)n*CC);
        const float4* nr = (const float4*)(noise + (size_t)n*CC);
        float m[CC], z[CC];
        float4 m0=mr[0],m1=mr[1],m2=mr[2], z0=nr[0],z1=nr[1],z2=nr[2];
        m[0]=m0.x;m[1]=m0.y;m[2]=m0.z;m[3]=m0.w;m[4]=m1.x;m[5]=m1.y;m[6]=m1.z;m[7]=m1.w;
        m[8]=m2.x;m[9]=m2.y;m[10]=m2.z;m[11]=m2.w;
        z[0]=z0.x;z[1]=z0.y;z[2]=z0.z;z[3]=z0.w;z[4]=z1.x;z[5]=z1.y;z[6]=z1.z;z[7]=z1.w;
        z[8]=z2.x;z[9]=z2.y;z[10]=z2.z;z[11]=z2.w;
#pragma unroll
        for (int c = 0; c < CC; ++c) h[c] = h[c]*m[c] + z[c]*(1.0f-m[c]);
    }
    float sv = 0.f, dv = 0.f;
    float o[CC];
#pragma unroll
    for (int oc = 0; oc < CC; ++oc) {
        float a = 0.f;
#pragma unroll
        for (int ic = 0; ic < CC; ++ic) a += h[ic]*W[oc*CC+ic];
        o[oc] = a;
        sv += a * a_s[oc]; dv += a * a_d[oc];
    }
    float4 r0, r1;
    r0.x = sv;
    r0.y = __uint_as_float(pk2(o[0], o[1]));
    r0.z = __uint_as_float(pk2(o[2], o[3]));
    r0.w = __uint_as_float(pk2(o[4], o[5]));
    r1.x = __uint_as_float(pk2(o[6], o[7]));
    r1.y = __uint_as_float(pk2(o[8], o[9]));
    r1.z = __uint_as_float(pk2(o[10], o[11]));
    r1.w = 0.f;
    rows[(size_t)n*2]   = r0;
    rows[(size_t)n*2+1] = r1;
    dval[n] = dv;
}

// ---------------- atomic-free hierarchical binning (3 phases) -------------
__global__ __launch_bounds__(256) void binA1_k(
    const int* __restrict__ e1, int* __restrict__ gcnt)
{
    __shared__ int lh[NB];
    const int tid = threadIdx.x;
    const int lo = blockIdx.x * CHUNK2, hi = lo + CHUNK2;
    for (int b = tid; b < NB; b += 256) lh[b] = 0;
    __syncthreads();
    for (int i = lo + tid; i < hi; i += 256) {
        int d = (i < EE) ? e1[i] : (i - EE);
        atomicAdd(&lh[d >> 7], 1);
    }
    __syncthreads();
    for (int b = tid; b < NB; b += 256)
        gcnt[(size_t)blockIdx.x*NB + b] = lh[b];
}

__global__ __launch_bounds__(512) void binscan_k(
    const int* __restrict__ gcnt, int* __restrict__ gbase, int* __restrict__ bcnt)
{
    __shared__ int sh[BINB2];
    const int b = blockIdx.x, t = threadIdx.x;
    int v = gcnt[(size_t)t*NB + b];
    sh[t] = v; __syncthreads();
    for (int off = 1; off < BINB2; off <<= 1) {
        int add = (t >= off) ? sh[t-off] : 0;
        __syncthreads();
        sh[t] += add;
        __syncthreads();
    }
    gbase[(size_t)b*BINB2 + t] = sh[t] - v;
    if (t == BINB2-1) bcnt[b] = sh[BINB2-1];
}

__global__ __launch_bounds__(256) void binA2_k(
    const int* __restrict__ e0, const int* __restrict__ e1,
    const int* __restrict__ gbase, unsigned* __restrict__ pairs)
{
    __shared__ int lbase[NB];
    __shared__ int lh[NB];
    const int tid = threadIdx.x;
    const int lo = blockIdx.x * CHUNK2, hi = lo + CHUNK2;
    for (int b = tid; b < NB; b += 256) {
        lbase[b] = gbase[(size_t)b*BINB2 + blockIdx.x];
        lh[b] = 0;
    }
    __syncthreads();
    for (int i = lo + tid; i < hi; i += 256) {
        int s, d;
        if (i < EE) { s = e0[i]; d = e1[i]; }
        else        { s = i - EE; d = s; }
        int b = d >> 7;
        int p = lbase[b] + atomicAdd(&lh[b], 1);
        if (p < BCAP)
            pairs[(size_t)b*BCAP + p] = ((unsigned)(d & 127) << 17) | (unsigned)s;
    }
}

// ---------------- per-bucket fine counting sort, IN PLACE ----------------
__global__ __launch_bounds__(1024) void binB_k(
    unsigned* __restrict__ pairs, const int* __restrict__ bcnt,
    int* __restrict__ cnt, int* __restrict__ offs)
{
    __shared__ unsigned ent[BCAP];
    __shared__ int lh[128], ls[128], lc[128];
    const int b = blockIdx.x, tid = threadIdx.x;
    const int n = min(bcnt[b], BCAP);
    for (int i = tid; i < n; i += 1024) ent[i] = pairs[(size_t)b*BCAP + i];
    if (tid < 128) lh[tid] = 0;
    __syncthreads();
    for (int i = tid; i < n; i += 1024) atomicAdd(&lh[ent[i] >> 17], 1);
    __syncthreads();
    if (tid == 0) { int run = 0; for (int j = 0; j < 128; ++j) { ls[j] = run; run += lh[j]; } }
    __syncthreads();
    if (tid < 128) {
        int node = b*128 + tid;
        cnt[node]  = lh[tid];
        offs[node] = b*BCAP + ls[tid];
        lc[tid]    = ls[tid];
    }
    __syncthreads();
    for (int i = tid; i < n; i += 1024) {
        unsigned v = ent[i];
        int dl = (int)(v >> 17);
        int p = atomicAdd(&lc[dl], 1);
        pairs[(size_t)b*BCAP + p] = v & 0x1FFFFu;
    }
}

// ---------------- GAT aggregation: 8 lanes/node, shfl reduce, NO atomics ---
__global__ __launch_bounds__(256) void gat_agg8_k(
    const unsigned* __restrict__ pairs, const int* __restrict__ cnt,
    const int* __restrict__ offs,
    const float4* __restrict__ rows, const float* __restrict__ dval,
    const float* __restrict__ bias,
    float* __restrict__ out, bf* __restrict__ outb, int dotanh)
{
    int g = blockIdx.x*32 + (threadIdx.x >> 3);
    int l = threadIdx.x & 7;
    if (g >= NN) return;
    int beg = offs[g], m = cnt[g];
    float dv = dval[g];
    float acc[CC] = {};
    float den = 0.f;
    for (int i = l; i < m; i += 8) {
        unsigned s = pairs[beg + i];
        float4 r0 = rows[(size_t)s*2];
        float4 r1 = rows[(size_t)s*2+1];
        float e = r0.x + dv;
        e = e > 0.f ? e : 0.2f*e;
        float w = __expf(e);
        den += w;
        unsigned p01 = __float_as_uint(r0.y), p23 = __float_as_uint(r0.z);
        unsigned p45 = __float_as_uint(r0.w), p67 = __float_as_uint(r1.x);
        unsigned p89 = __float_as_uint(r1.y), pab = __float_as_uint(r1.z);
        acc[0]  += w*lo16(p01); acc[1]  += w*hi16(p01);
        acc[2]  += w*lo16(p23); acc[3]  += w*hi16(p23);
        acc[4]  += w*lo16(p45); acc[5]  += w*hi16(p45);
        acc[6]  += w*lo16(p67); acc[7]  += w*hi16(p67);
        acc[8]  += w*lo16(p89); acc[9]  += w*hi16(p89);
        acc[10] += w*lo16(pab); acc[11] += w*hi16(pab);
    }
#pragma unroll
    for (int off = 1; off < 8; off <<= 1) {
        den += __shfl_xor(den, off);
#pragma unroll
        for (int c = 0; c < CC; ++c) acc[c] += __shfl_xor(acc[c], off);
    }
    if (l == 0) {
        float inv = 1.f / den;
        float r[CC];
#pragma unroll
        for (int c = 0; c < CC; ++c) {
            r[c] = acc[c]*inv + bias[c];
            if (dotanh) r[c] = tanhf(r[c]);
        }
        if (out) {
            float4* orow = (float4*)(out + (size_t)g*CC);
            orow[0] = make_float4(r[0],r[1],r[2],r[3]);
            orow[1] = make_float4(r[4],r[5],r[6],r[7]);
            orow[2] = make_float4(r[8],r[9],r[10],r[11]);
        }
        if (outb) {
            s4v* brow = (s4v*)(outb + (size_t)g*CC);
            s4v b0, b1, b2;
            b0[0]=bfbits(r[0]); b0[1]=bfbits(r[1]); b0[2]=bfbits(r[2]); b0[3]=bfbits(r[3]);
            b1[0]=bfbits(r[4]); b1[1]=bfbits(r[5]); b1[2]=bfbits(r[6]); b1[3]=bfbits(r[7]);
            b2[0]=bfbits(r[8]); b2[1]=bfbits(r[9]); b2[2]=bfbits(r[10]); b2[3]=bfbits(r[11]);
            brow[0]=b0; brow[1]=b1; brow[2]=b2;
        }
    }
}

// ---------------- bf16 MFMA NT GEMM (LDS-swizzled, TBM in {64,128}) -------
// vtmode: batch z1==2 writes Cb in transposed V layout [bh][d][s]
template<int TBM>
__global__ __launch_bounds__(256) void gemm_bt(
    const bf* __restrict__ A, const bf* __restrict__ B,
    const float* __restrict__ bias, float* __restrict__ Cf, bf* __restrict__ Cb,
    int K, int lda, int ldb, int ldc,
    long long sA1, long long sA2, long long sB1, long long sB2,
    long long sC1, long long sC2, int bdiv, long long sBias,
    float scale, int relu, int vtmode)
{
    constexpr int MI = TBM/32;
    __shared__ bf As[TBM*32];
    __shared__ bf Bs[64*32];
    const int tid = threadIdx.x, lane = tid & 63, wave = tid >> 6;
    const int z = blockIdx.z, z1 = z / bdiv, z2 = z % bdiv;
    const bf* Ab = A + z1*sA1 + z2*sA2;
    const bf* Bb = B + z1*sB1 + z2*sB2;
    const int bm = blockIdx.y * TBM, bn = blockIdx.x * 64;
    const int l4 = lane >> 2;
    const int swz0 = (l4 >> 1) & 3;
    const int lc = (((lane & 3) ^ swz0) * 8);
    const int arow0 = wave*(TBM/4) + l4;
    const int brow  = wave*16 + l4;
    const int wm = wave >> 1, wn = wave & 1;
    const int fr = lane & 15;
    const int gsw = (((lane >> 4) ^ ((fr >> 1) & 3)) * 8);
    f4v acc[MI][2] = {};

    for (int k0 = 0; k0 < K; k0 += 32) {
        gl16(Ab + (size_t)(bm + arow0)*lda + k0 + lc, As + wave*(TBM/4)*32);
        if constexpr (TBM == 128)
            gl16(Ab + (size_t)(bm + arow0 + 16)*lda + k0 + lc, As + wave*1024 + 512);
        gl16(Bb + (size_t)(bn + brow )*ldb + k0 + lc, Bs + wave*512);
        __syncthreads();
        s8v af[MI], bfv[2];
#pragma unroll
        for (int mi = 0; mi < MI; ++mi)
            af[mi] = *(const s8v*)&As[(wm*(TBM/2) + mi*16 + fr)*32 + gsw];
#pragma unroll
        for (int nj = 0; nj < 2; ++nj)
            bfv[nj] = *(const s8v*)&Bs[(wn*32 + nj*16 + fr)*32 + gsw];
#pragma unroll
        for (int mi = 0; mi < MI; ++mi)
#pragma unroll
            for (int nj = 0; nj < 2; ++nj)
                acc[mi][nj] = __builtin_amdgcn_mfma_f32_16x16x32_bf16(
                    af[mi], bfv[nj], acc[mi][nj], 0, 0, 0);
        __syncthreads();
    }

    const float* bp = bias ? bias + z1*sBias : nullptr;
    if (vtmode && z1 == 2) {
        bf* vt = Cb + 2*sC1;
#pragma unroll
        for (int mi = 0; mi < MI; ++mi) {
#pragma unroll
            for (int nj = 0; nj < 2; ++nj) {
                int col = bn + wn*32 + nj*16 + fr;
                float bv = bp ? bp[col] : 0.f;
                int row0 = bm + wm*(TBM/2) + mi*16 + (lane>>4)*4;
                int b = row0 >> 9, s0 = row0 & 511;
                int h = col / HDI, dd = col - h*HDI;
                s4v pk;
#pragma unroll
                for (int r = 0; r < 4; ++r)
                    pk[r] = bfbits(acc[mi][nj][r] + bv);
                *(s4v*)&vt[((size_t)((b*HH + h)*HDI + dd))*SS + s0] = pk;
            }
        }
        return;
    }
    float* Cfb = Cf ? Cf + z1*sC1 + z2*sC2 : nullptr;
    bf*    Cbb = Cb ? Cb + z1*sC1 + z2*sC2 : nullptr;
#pragma unroll
    for (int mi = 0; mi < MI; ++mi) {
#pragma unroll
        for (int nj = 0; nj < 2; ++nj) {
            int col = bn + wn*32 + nj*16 + fr;
            float bv = bp ? bp[col] : 0.f;
#pragma unroll
            for (int r = 0; r < 4; ++r) {
                int row = bm + wm*(TBM/2) + mi*16 + (lane>>4)*4 + r;
                float vv = (acc[mi][nj][r] + bv) * scale;
                if (relu) vv = fmaxf(vv, 0.f);
                if (Cfb) Cfb[(size_t)row*ldc + col] = vv;
                if (Cbb) Cbb[(size_t)row*ldc + col] = __float2bfloat16(vv);
            }
        }
    }
}

// ---------------- direct conv GEMM, 128x64 tile, split-K ------------------
// A logical: [M=B*Lout][K=3*CIN] from padded activations [B][Lin+2][CIN].
// MODE 0: s1p1 row=l+kk; 1: s2 p(0,1) row=2l+kk+1; 2: up x2 row=(l+kk+1)>>1;
// MODE 3: concat(A0,A1) halves s1p1. Writes f32 partials.
template<int CIN, int MODE>
__global__ __launch_bounds__(256) void conv128_k(
    const bf* __restrict__ A0, const bf* __restrict__ A1,
    const bf* __restrict__ Bw, float* __restrict__ Cpart,
    int K, int M, int N, int Lout, int Lin, int splitk)
{
    __shared__ bf As[128*32];
    __shared__ bf Bs[64*32];
    const int tid = threadIdx.x, lane = tid & 63, wave = tid >> 6;
    const int bm = blockIdx.y * 128, bn = blockIdx.x * 64;
    const int kchunk = K / splitk;
    const int kbeg = blockIdx.z * kchunk, kend = kbeg + kchunk;
    const int l4 = lane >> 2;
    const int swz0 = (l4 >> 1) & 3;
    const int lc = (((lane & 3) ^ swz0) * 8);
    const int arowA = bm + wave*32 + l4;
    const int arowB = arowA + 16;
    const int brow  = bn + wave*16 + l4;
    const int abA = arowA / Lout, alA = arowA % Lout;
    const int abB = arowB / Lout, alB = arowB % Lout;
    const int wm = wave >> 1, wn = wave & 1;
    const int fr = lane & 15;
    const int gsw = (((lane >> 4) ^ ((fr >> 1) & 3)) * 8);
    f4v acc[4][2] = {};

    for (int k0 = kbeg; k0 < kend; k0 += 32) {
        int kk  = k0 / CIN;
        int ci0 = k0 - kk*CIN;
        int rowA, rowB;
        if constexpr (MODE == 1)      { rowA = 2*alA + kk + 1; rowB = 2*alB + kk + 1; }
        else if constexpr (MODE == 2) { rowA = (alA + kk + 1) >> 1; rowB = (alB + kk + 1) >> 1; }
        else                          { rowA = alA + kk; rowB = alB + kk; }
        const bf *srcA, *srcB;
        if constexpr (MODE == 3) {
            constexpr int CH = CIN/2;
            bool lohalf = ci0 < CH;
            const bf* base = lohalf ? A0 : A1;
            int cc = lohalf ? ci0 : ci0 - CH;
            srcA = base + ((size_t)(abA*(Lin+2) + rowA))*CH + cc;
            srcB = base + ((size_t)(abB*(Lin+2) + rowB))*CH + cc;
        } else {
            srcA = A0 + ((size_t)(abA*(Lin+2) + rowA))*CIN + ci0;
            srcB = A0 + ((size_t)(abB*(Lin+2) + rowB))*CIN + ci0;
        }
        gl16(srcA + lc, As + wave*1024);
        gl16(srcB + lc, As + wave*1024 + 512);
        gl16(Bw + (size_t)brow*K + k0 + lc, Bs + wave*512);
        __syncthreads();
        s8v af[4], bfv[2];
#pragma unroll
        for (int mi = 0; mi < 4; ++mi)
            af[mi] = *(const s8v*)&As[(wm*64 + mi*16 + fr)*32 + gsw];
#pragma unroll
        for (int nj = 0; nj < 2; ++nj)
            bfv[nj] = *(const s8v*)&Bs[(wn*32 + nj*16 + fr)*32 + gsw];
#pragma unroll
        for (int mi = 0; mi < 4; ++mi)
#pragma unroll
            for (int nj = 0; nj < 2; ++nj)
                acc[mi][nj] = __builtin_amdgcn_mfma_f32_16x16x32_bf16(
                    af[mi], bfv[nj], acc[mi][nj], 0, 0, 0);
        __syncthreads();
    }

    float* Cp = Cpart + (size_t)blockIdx.z * M * N;
#pragma unroll
    for (int mi = 0; mi < 4; ++mi)
#pragma unroll
        for (int nj = 0; nj < 2; ++nj) {
            int col = bn + wn*32 + nj*16 + fr;
#pragma unroll
            for (int r = 0; r < 4; ++r) {
                int row = bm + wm*64 + mi*16 + (lane>>4)*4 + r;
                Cp[(size_t)row*N + col] = acc[mi][nj][r];
            }
        }
}

// ---------------- conv epilogue: sum nsplit partials + bias (+relu) -------
__global__ __launch_bounds__(256) void convepi_k(
    const float* __restrict__ part, const float* __restrict__ bias,
    bf* __restrict__ outb, float* __restrict__ outf,
    int M, int N, int Lout, int relu, int nsplit)
{
    int total = M * (N >> 3);
    int i = blockIdx.x*256 + threadIdx.x;
    if (i >= total) return;
    int c8 = (i % (N >> 3)) * 8;
    int row = i / (N >> 3);
    float v[8];
#pragma unroll
    for (int j = 0; j < 8; ++j) v[j] = bias[c8+j];
    for (int z = 0; z < nsplit; ++z) {
        const float* p = part + (size_t)z*M*N + (size_t)row*N + c8;
#pragma unroll
        for (int j = 0; j < 8; ++j) v[j] += p[j];
    }
    if (relu) {
#pragma unroll
        for (int j = 0; j < 8; ++j) v[j] = fmaxf(v[j], 0.f);
    }
    if (outb) {
        int b = row / Lout, l = row % Lout;
        s8v pk;
#pragma unroll
        for (int j = 0; j < 8; ++j) pk[j] = bfbits(v[j]);
        *(s8v*)&outb[((size_t)(b*(Lout+2) + l + 1))*N + c8] = pk;
    }
    if (outf) {
        float4* o = (float4*)(outf + (size_t)row*N + c8);
        o[0] = make_float4(v[0],v[1],v[2],v[3]);
        o[1] = make_float4(v[4],v[5],v[6],v[7]);
    }
}

// ---------------- unified prep: casts + bias packs + pad-zeros ------------
struct PJob { int type; const float* src; void* dst; int a; int b; };
struct PJobs { PJob j[14]; };
__global__ __launch_bounds__(256) void prep_k(PJobs J)
{
    PJob jb = J.j[blockIdx.y];
    if (jb.type == 0) {
        for (int i = blockIdx.x*256 + threadIdx.x; i < jb.a; i += gridDim.x*256) {
            float4 v = ((const float4*)jb.src)[i];
            s4v p;
            p[0]=bfbits(v.x); p[1]=bfbits(v.y); p[2]=bfbits(v.z); p[3]=bfbits(v.w);
            ((s4v*)jb.dst)[i] = p;
        }
    } else if (jb.type == 1) {
        for (int i = blockIdx.x*256 + threadIdx.x; i < jb.a; i += gridDim.x*256)
            ((float4*)jb.dst)[i] = ((const float4*)jb.src)[i];
    } else {
        int n8 = BB * 2 * (jb.b >> 3);
        for (int i = blockIdx.x*256 + threadIdx.x; i < n8; i += gridDim.x*256) {
            int c8 = i % (jb.b >> 3); int r = i / (jb.b >> 3);
            int bb = r >> 1; int row = (r & 1) ? (jb.a + 1) : 0;
            s8v z = {0,0,0,0,0,0,0,0};
            *(s8v*)&((bf*)jb.dst)[((size_t)(bb*(jb.a+2) + row))*jb.b + c8*8] = z;
        }
    }
}

// ---------------- 5-job conv weight transpose -----------------------------
struct WJob { const float* w; bf* wT; int Cout; int Cin; };
struct WJobs { WJob j[5]; };
__global__ __launch_bounds__(256) void wtrans5_k(WJobs J)
{
    WJob jb = J.j[blockIdx.y];
    int n8 = jb.Cout * 3 * (jb.Cin >> 3);
    for (int i = blockIdx.x*256 + threadIdx.x; i < n8; i += gridDim.x*256) {
        int c8 = i % (jb.Cin >> 3); int r = i / (jb.Cin >> 3);
        int kk = r % 3; int co = r / 3;
        int ci = c8 * 8;
        s8v ov;
#pragma unroll
        for (int j = 0; j < 8; ++j)
            ov[j] = bfbits(jb.w[((size_t)co*jb.Cin + ci + j)*3 + kk]);
        *(s8v*)&jb.wT[(size_t)co*3*jb.Cin + (size_t)kk*jb.Cin + ci] = ov;
    }
}

// ---------------- softmax rows of 512, f32 -> bf16 ----------------
__global__ __launch_bounds__(256) void softmax_k(
    const float* __restrict__ S, bf* __restrict__ P)
{
    int row = blockIdx.x; size_t base = (size_t)row * SS;
    int tid = threadIdx.x;
    __shared__ float red[256];
    float v0 = S[base+tid], v1 = S[base+tid+256];
    red[tid] = fmaxf(v0, v1); __syncthreads();
    for (int off = 128; off > 0; off >>= 1) {
        if (tid < off) red[tid] = fmaxf(red[tid], red[tid+off]);
        __syncthreads();
    }
    float mx = red[0]; __syncthreads();
    float e0 = __expf(v0-mx), e1 = __expf(v1-mx);
    red[tid] = e0+e1; __syncthreads();
    for (int off = 128; off > 0; off >>= 1) {
        if (tid < off) red[tid] += red[tid+off];
        __syncthreads();
    }
    float inv = 1.f / red[0];
    P[base+tid]     = __float2bfloat16(e0*inv);
    P[base+tid+256] = __float2bfloat16(e1*inv);
}

// ---------------- layernorm over D=576 (ob optionally padded-layout) ------
__global__ __launch_bounds__(256) void ln_k(
    const float* __restrict__ a, const float* __restrict__ r,
    const float* __restrict__ g, const float* __restrict__ be,
    float* __restrict__ out, bf* __restrict__ ob, int padout)
{
    int row = blockIdx.x; int tid = threadIdx.x;
    __shared__ float red[256], red2[256];
    size_t base = (size_t)row * DD;
    size_t base2 = padout ? ((size_t)(row + 2*(row/SS) + 1))*DD : base;
    float x0 = a[base+tid]      + r[base+tid];
    float x1 = a[base+tid+256]  + r[base+tid+256];
    float x2 = (tid < 64) ? (a[base+tid+512] + r[base+tid+512]) : 0.f;
    float s  = x0+x1+x2;
    float s2 = x0*x0 + x1*x1 + x2*x2;
    red[tid] = s; red2[tid] = s2; __syncthreads();
    for (int off = 128; off > 0; off >>= 1) {
        if (tid < off) { red[tid] += red[tid+off]; red2[tid] += red2[tid+off]; }
        __syncthreads();
    }
    float mean = red[0] / (float)DD;
    float var  = red2[0] / (float)DD - mean*mean;
    float inv = rsqrtf(var + 1e-5f);
    float y0 = (x0-mean)*inv*g[tid]     + be[tid];
    float y1 = (x1-mean)*inv*g[tid+256] + be[tid+256];
    if (out) { out[base+tid] = y0; out[base+tid+256] = y1; }
    if (ob)  { ob[base2+tid] = __float2bfloat16(y0); ob[base2+tid+256] = __float2bfloat16(y1); }
    if (tid < 64) {
        float y2 = (x2-mean)*inv*g[tid+512] + be[tid+512];
        if (out) out[base+tid+512] = y2;
        if (ob)  ob[base2+tid+512] = __float2bfloat16(y2);
    }
}

// ---------------- launch ----------------
extern "C" void kernel_launch(void* const* d_in, const int* in_sizes, int n_in,
                              void* d_out, int out_size, void* d_ws, size_t ws_size,
                              hipStream_t stream)
{
    const int*   edge   = (const int*)  d_in[0];
    const float* x      = (const float*)d_in[1];
    const float* mask   = (const float*)d_in[2];
    const float* noise  = (const float*)d_in[3];
    const float* W_enc  = (const float*)d_in[4];
    const float* asrc_e = (const float*)d_in[5];
    const float* adst_e = (const float*)d_in[6];
    const float* b_enc  = (const float*)d_in[7];
    const float* Wq = (const float*)d_in[8];  const float* bq = (const float*)d_in[9];
    const float* Wk = (const float*)d_in[10]; const float* bk = (const float*)d_in[11];
    const float* Wv = (const float*)d_in[12]; const float* bv = (const float*)d_in[13];
    const float* Wo = (const float*)d_in[14]; const float* bo = (const float*)d_in[15];
    const float* ln1g = (const float*)d_in[16]; const float* ln1b = (const float*)d_in[17];
    const float* W1 = (const float*)d_in[18]; const float* b1 = (const float*)d_in[19];
    const float* W2 = (const float*)d_in[20]; const float* b2 = (const float*)d_in[21];
    const float* ln2g = (const float*)d_in[22]; const float* ln2b = (const float*)d_in[23];
    const float* enc1_w = (const float*)d_in[24]; const float* enc1_b = (const float*)d_in[25];
    const float* down_w = (const float*)d_in[26]; const float* down_b = (const float*)d_in[27];
    const float* bott_w = (const float*)d_in[28]; const float* bott_b = (const float*)d_in[29];
    const float* up_w   = (const float*)d_in[30]; const float* up_b   = (const float*)d_in[31];
    const float* dec_w  = (const float*)d_in[32]; const float* dec_b  = (const float*)d_in[33];
    const float* W_dec  = (const float*)d_in[34];
    const float* asrc_d = (const float*)d_in[35];
    const float* adst_d = (const float*)d_in[36];
    const float* b_dec  = (const float*)d_in[37];
    float* out = (float*)d_out;

    float* ws = (float*)d_ws;
    // float-unit offsets; total 23,632,320 floats = 94.5 MB
    float4*   rows  = (float4*)ws;              // 786432 f
    float*    dval  = ws + 786432;              // 98304
    int*      cnt   = (int*)(ws + 884736);      // 98304
    int*      offs  = (int*)(ws + 983040);      // 98304
    unsigned* pairs = (unsigned*)(ws + 1376256);// 1966080 u32
    int*      bcnt  = (int*)(ws + 3342336);     // 1024
    float*    t     = ws + 3343360;             // 1179648
    bf*       tb    = (bf*)(ws + 4523008);      // 589824 f
    bf*       qb    = (bf*)(ws + 5112832);      // 589824 f
    bf*       kb    = (bf*)(ws + 5702656);      // 589824 f
    bf*       vb    = (bf*)(ws + 6292480);      // 589824 f (holds V TRANSPOSED)
    float*    big   = ws + 6882304;             // 4718592 f shared scratch
    int*      gcnt  = (int*)big;                // sort: 393216
    int*      gbase = (int*)(big + 393216);     // sort: 393216
    float*    scores = big;                     // attn: 3145728 f
    bf*       Pb    = (bf*)(big + 3145728);     // attn: 1572864 f
    bf*       wTbott = (bf*)big;                // conv: 1990656 f
    float*    o     = ws + 11600896;            // 1179648
    float*    parts = ws + 11600896;            // conv: 4718592 f (o..ff1b dead)
    float*    t1    = ws + 12780544;            // 1179648
    bf*       t1b   = (bf*)(ws + 13960192);     // 589824 f
    bf*       ff1b  = (bf*)(ws + 14550016);     // 2097152 f
    bf*       t2p   = (bf*)(ws + 16647168);     // 592128 f  [4][514][576]
    bf*       e1p   = (bf*)(ws + 17239296);     // 592128 f  [4][514][576]
    bf*       d1p   = (bf*)(ws + 17831424);     // 594432 f  [4][258][1152]
    bf*       btbp  = (bf*)(ws + 18425856);     // 594432 f  [4][258][1152]
    bf*       upp   = (bf*)(ws + 19020288);     // 592128 f  [4][514][576]
    float*    dec   = ws + 19612416;            // 1179648
    bf*       wTb   = (bf*)(ws + 20792064);     // 995328 f
    bf*       Wqb   = (bf*)(ws + 21787392);     // 165888 f each
    bf*       Wkb   = (bf*)(ws + 21953280);
    bf*       Wvb   = (bf*)(ws + 22119168);
    bf*       Wob   = (bf*)(ws + 22285056);
    bf*       W1b   = (bf*)(ws + 22450944);     // 589824
    bf*       W2b   = (bf*)(ws + 23040768);     // 589824
    float*    biasQKV = ws + 23630592;          // 1728, end 23632320
    bf*       vt    = vb;
    bf*       attnO = qb;
    bf*       wTenc  = wTb;
    bf*       wTdown = (bf*)t;
    bf*       wTup   = kb;
    bf*       wTdec  = tb;

    const int* e0 = edge;
    const int* e1i = edge + EE;

    // ---- 0. atomic-free binning + in-place fine sort ----
    binA1_k<<<BINB2, 256, 0, stream>>>(e1i, gcnt);
    binscan_k<<<NB, BINB2, 0, stream>>>(gcnt, gbase, bcnt);
    binA2_k<<<BINB2, 256, 0, stream>>>(e0, e1i, gbase, pairs);
    binB_k<<<NB, 1024, 0, stream>>>(pairs, bcnt, cnt, offs);

    // ---- unified prep ----
    {
        PJobs J;
        J.j[0]  = { 0, Wq, Wqb, DD*DD/4, 0 };
        J.j[1]  = { 0, Wk, Wkb, DD*DD/4, 0 };
        J.j[2]  = { 0, Wv, Wvb, DD*DD/4, 0 };
        J.j[3]  = { 0, Wo, Wob, DD*DD/4, 0 };
        J.j[4]  = { 0, W1, W1b, FFD*DD/4, 0 };
        J.j[5]  = { 0, W2, W2b, FFD*DD/4, 0 };
        J.j[6]  = { 1, bq, biasQKV,        DD/4, 0 };
        J.j[7]  = { 1, bk, biasQKV + DD,   DD/4, 0 };
        J.j[8]  = { 1, bv, biasQKV + 2*DD, DD/4, 0 };
        J.j[9]  = { 2, nullptr, t2p,  512, 576 };
        J.j[10] = { 2, nullptr, e1p,  512, 576 };
        J.j[11] = { 2, nullptr, d1p,  256, 1152 };
        J.j[12] = { 2, nullptr, btbp, 256, 1152 };
        J.j[13] = { 2, nullptr, upp,  512, 576 };
        prep_k<<<dim3(576, 14), 256, 0, stream>>>(J);
    }

    // ---- 1. GAT encoder ----
    gat_node_k<<<NN/256, 256, 0, stream>>>(x, mask, noise, W_enc, asrc_e, adst_e,
                                           rows, dval, 1);
    gat_agg8_k<<<NN/32, 256, 0, stream>>>(pairs, cnt, offs, rows, dval, b_enc,
                                          t, tb, 0);

    // ---- 2. transformer layer ----
    gemm_bt<128><<<dim3(9,16,3), 256, 0, stream>>>(tb, Wqb, biasQKV, nullptr, qb,
        DD, DD, DD, DD,
        0,0, (long long)DD*DD,0, (long long)MR*DD,0, 1, DD, 1.f, 0, 1);
    gemm_bt<128><<<dim3(8,4,12), 256, 0, stream>>>(qb, kb, nullptr, scores, nullptr,
        HDI, DD, DD, SS,
        (long long)SS*DD, HDI, (long long)SS*DD, HDI,
        3LL*SS*SS, (long long)SS*SS, HH, 0, ATT_SCALE, 0, 0);
    softmax_k<<<12*SS, 256, 0, stream>>>(scores, Pb);
    gemm_bt<64><<<dim3(3,8,12), 256, 0, stream>>>(Pb, vt, nullptr, nullptr, attnO,
        SS, SS, SS, DD,
        3LL*SS*SS, (long long)SS*SS, 3LL*HDI*SS, (long long)HDI*SS,
        (long long)SS*DD, HDI, HH, 0, 1.f, 0, 0);
    gemm_bt<64><<<dim3(9,32,1), 256, 0, stream>>>(attnO, Wob, bo, o, nullptr,
        DD, DD, DD, DD, 0,0,0,0,0,0, 1, 0, 1.f, 0, 0);
    ln_k<<<MR, 256, 0, stream>>>(t, o, ln1g, ln1b, t1, t1b, 0);
    gemm_bt<128><<<dim3(32,16,1), 256, 0, stream>>>(t1b, W1b, b1, nullptr, ff1b,
        DD, DD, DD, FFD, 0,0,0,0,0,0, 1, 0, 1.f, 1, 0);
    gemm_bt<64><<<dim3(9,32,1), 256, 0, stream>>>(ff1b, W2b, b2, o, nullptr,
        FFD, FFD, FFD, DD, 0,0,0,0,0,0, 1, 0, 1.f, 0, 0);
    ln_k<<<MR, 256, 0, stream>>>(t1, o, ln2g, ln2b, nullptr, t2p, 1);

    // ---- 3. UNet1d: batched weight-transpose, then 128-row conv GEMMs ----
    {
        WJobs W5;
        W5.j[0] = { enc1_w, wTenc,  576,  576 };
        W5.j[1] = { down_w, wTdown, 1152, 576 };
        W5.j[2] = { bott_w, wTbott, 1152, 1152 };
        W5.j[3] = { up_w,   wTup,   576,  1152 };
        W5.j[4] = { dec_w,  wTdec,  576,  1152 };
        wtrans5_k<<<dim3(1024, 5), 256, 0, stream>>>(W5);
    }
    // enc1: 576->576, L=512, s1p1, K=1728, splitk=3 (kchunk 576 = 18x32)
    conv128_k<576,0><<<dim3(9,16,3), 256, 0, stream>>>(t2p, nullptr, wTenc, parts,
        1728, 2048, 576, 512, 512, 3);
    convepi_k<<<576, 256, 0, stream>>>(parts, enc1_b, e1p, nullptr, 2048, 576, 512, 1, 3);
    // down: 576->1152, stride2 pad(0,1), splitk=3
    conv128_k<576,1><<<dim3(18,8,3), 256, 0, stream>>>(e1p, nullptr, wTdown, parts,
        1728, 1024, 1152, 256, 512, 3);
    convepi_k<<<576, 256, 0, stream>>>(parts, down_b, d1p, nullptr, 1024, 1152, 256, 1, 3);
    // bott: 1152->1152, L=256, s1p1, K=3456, splitk=4 (kchunk 864 = 27x32)
    conv128_k<1152,0><<<dim3(18,8,4), 256, 0, stream>>>(d1p, nullptr, wTbott, parts,
        3456, 1024, 1152, 256, 256, 4);
    convepi_k<<<576, 256, 0, stream>>>(parts, bott_b, btbp, nullptr, 1024, 1152, 256, 1, 4);
    // up: repeat x2 then 1152->576, L=512, splitk=4
    conv128_k<1152,2><<<dim3(9,16,4), 256, 0, stream>>>(btbp, nullptr, wTup, parts,
        3456, 2048, 576, 512, 256, 4);
    convepi_k<<<576, 256, 0, stream>>>(parts, up_b, upp, nullptr, 2048, 576, 512, 1, 4);
    // dec: concat(up, e1) 1152->576, L=512, no relu, f32 out, splitk=4
    conv128_k<1152,3><<<dim3(9,16,4), 256, 0, stream>>>(upp, e1p, wTdec, parts,
        3456, 2048, 576, 512, 512, 4);
    convepi_k<<<576, 256, 0, stream>>>(parts, dec_b, nullptr, dec, 2048, 576, 512, 0, 4);

    // ---- 4. GAT decoder + tanh ----
    gat_node_k<<<NN/256, 256, 0, stream>>>(dec, nullptr, nullptr, W_dec, asrc_d, adst_d,
                                           rows, dval, 0);
    gat_agg8_k<<<NN/32, 256, 0, stream>>>(pairs, cnt, offs, rows, dval, b_dec,
                                          out, nullptr, 1);
}

// Round 14
// 348.202 us; speedup vs baseline: 1.2554x; 1.0303x over previous
//
#include <hip/hip_runtime.h>
#include <hip/hip_bf16.h>
#include <math.h>

// ---------------- problem constants ----------------
#define NN 98304
#define CC 12
#define EE 1572864
#define ETOT (EE + NN)
#define BB 4
#define SS 512
#define DD 576
#define HH 3
#define HDI 192
#define FFD 2048
#define MR (BB*SS)
#define ND (NN*CC)
#define ATT_SCALE 0.07216878364870323f
#define NB 768
#define BCAP 2560
#define BINB2 512
#define CHUNK2 3264

typedef __hip_bfloat16 bf;
typedef __attribute__((ext_vector_type(8))) short s8v;
typedef __attribute__((ext_vector_type(4))) short s4v;
typedef __attribute__((ext_vector_type(4))) float f4v;

__device__ __forceinline__ void gl16(const void* g, void* l) {
    __builtin_amdgcn_global_load_lds(
        (const __attribute__((address_space(1))) unsigned int*)g,
        (__attribute__((address_space(3))) unsigned int*)l, 16, 0, 0);
}
__device__ __forceinline__ short bfbits(float f) {
    bf t = __float2bfloat16(f);
    return *(short*)&t;
}
__device__ __forceinline__ unsigned pk2(float a, float b) {
    return (unsigned)(unsigned short)bfbits(a) |
           ((unsigned)(unsigned short)bfbits(b) << 16);
}
__device__ __forceinline__ float lo16(unsigned v) { return __uint_as_float(v << 16); }
__device__ __forceinline__ float hi16(unsigned v) { return __uint_as_float(v & 0xffff0000u); }

// ---------------- GAT: node transform -> packed 32B rows ----------------
__global__ __launch_bounds__(256) void gat_node_k(
    const float* __restrict__ xin, const float* __restrict__ mask,
    const float* __restrict__ noise,
    const float* __restrict__ W, const float* __restrict__ a_s,
    const float* __restrict__ a_d,
    float4* __restrict__ rows, float* __restrict__ dval,
    int blend)
{
    int n = blockIdx.x * 256 + threadIdx.x;
    if (n >= NN) return;
    const float4* xr = (const float4*)(xin + (size_t)n*CC);
    float h[CC];
    float4 h0 = xr[0], h1 = xr[1], h2 = xr[2];
    h[0]=h0.x; h[1]=h0.y; h[2]=h0.z; h[3]=h0.w;
    h[4]=h1.x; h[5]=h1.y; h[6]=h1.z; h[7]=h1.w;
    h[8]=h2.x; h[9]=h2.y; h[10]=h2.z; h[11]=h2.w;
    if (blend) {
        const float4* mr = (const float4*)(mask  + (size_t)n*CC);
        const float4* nr = (const float4*)(noise + (size_t)n*CC);
        float m[CC], z[CC];
        float4 m0=mr[0],m1=mr[1],m2=mr[2], z0=nr[0],z1=nr[1],z2=nr[2];
        m[0]=m0.x;m[1]=m0.y;m[2]=m0.z;m[3]=m0.w;m[4]=m1.x;m[5]=m1.y;m[6]=m1.z;m[7]=m1.w;
        m[8]=m2.x;m[9]=m2.y;m[10]=m2.z;m[11]=m2.w;
        z[0]=z0.x;z[1]=z0.y;z[2]=z0.z;z[3]=z0.w;z[4]=z1.x;z[5]=z1.y;z[6]=z1.z;z[7]=z1.w;
        z[8]=z2.x;z[9]=z2.y;z[10]=z2.z;z[11]=z2.w;
#pragma unroll
        for (int c = 0; c < CC; ++c) h[c] = h[c]*m[c] + z[c]*(1.0f-m[c]);
    }
    float sv = 0.f, dv = 0.f;
    float o[CC];
#pragma unroll
    for (int oc = 0; oc < CC; ++oc) {
        float a = 0.f;
#pragma unroll
        for (int ic = 0; ic < CC; ++ic) a += h[ic]*W[oc*CC+ic];
        o[oc] = a;
        sv += a * a_s[oc]; dv += a * a_d[oc];
    }
    float4 r0, r1;
    r0.x = sv;
    r0.y = __uint_as_float(pk2(o[0], o[1]));
    r0.z = __uint_as_float(pk2(o[2], o[3]));
    r0.w = __uint_as_float(pk2(o[4], o[5]));
    r1.x = __uint_as_float(pk2(o[6], o[7]));
    r1.y = __uint_as_float(pk2(o[8], o[9]));
    r1.z = __uint_as_float(pk2(o[10], o[11]));
    r1.w = 0.f;
    rows[(size_t)n*2]   = r0;
    rows[(size_t)n*2+1] = r1;
    dval[n] = dv;
}

// ---------------- atomic-free hierarchical binning (3 phases) -------------
__global__ __launch_bounds__(256) void binA1_k(
    const int* __restrict__ e1, int* __restrict__ gcnt)
{
    __shared__ int lh[NB];
    const int tid = threadIdx.x;
    const int lo = blockIdx.x * CHUNK2, hi = lo + CHUNK2;
    for (int b = tid; b < NB; b += 256) lh[b] = 0;
    __syncthreads();
    for (int i = lo + tid; i < hi; i += 256) {
        int d = (i < EE) ? e1[i] : (i - EE);
        atomicAdd(&lh[d >> 7], 1);
    }
    __syncthreads();
    for (int b = tid; b < NB; b += 256)
        gcnt[(size_t)blockIdx.x*NB + b] = lh[b];
}

__global__ __launch_bounds__(512) void binscan_k(
    const int* __restrict__ gcnt, int* __restrict__ gbase, int* __restrict__ bcnt)
{
    __shared__ int sh[BINB2];
    const int b = blockIdx.x, t = threadIdx.x;
    int v = gcnt[(size_t)t*NB + b];
    sh[t] = v; __syncthreads();
    for (int off = 1; off < BINB2; off <<= 1) {
        int add = (t >= off) ? sh[t-off] : 0;
        __syncthreads();
        sh[t] += add;
        __syncthreads();
    }
    gbase[(size_t)b*BINB2 + t] = sh[t] - v;
    if (t == BINB2-1) bcnt[b] = sh[BINB2-1];
}

__global__ __launch_bounds__(256) void binA2_k(
    const int* __restrict__ e0, const int* __restrict__ e1,
    const int* __restrict__ gbase, unsigned* __restrict__ pairs)
{
    __shared__ int lbase[NB];
    __shared__ int lh[NB];
    const int tid = threadIdx.x;
    const int lo = blockIdx.x * CHUNK2, hi = lo + CHUNK2;
    for (int b = tid; b < NB; b += 256) {
        lbase[b] = gbase[(size_t)b*BINB2 + blockIdx.x];
        lh[b] = 0;
    }
    __syncthreads();
    for (int i = lo + tid; i < hi; i += 256) {
        int s, d;
        if (i < EE) { s = e0[i]; d = e1[i]; }
        else        { s = i - EE; d = s; }
        int b = d >> 7;
        int p = lbase[b] + atomicAdd(&lh[b], 1);
        if (p < BCAP)
            pairs[(size_t)b*BCAP + p] = ((unsigned)(d & 127) << 17) | (unsigned)s;
    }
}

// ---------------- per-bucket fine counting sort, IN PLACE ----------------
__global__ __launch_bounds__(1024) void binB_k(
    unsigned* __restrict__ pairs, const int* __restrict__ bcnt,
    int* __restrict__ cnt, int* __restrict__ offs)
{
    __shared__ unsigned ent[BCAP];
    __shared__ int lh[128], ls[128], lc[128];
    const int b = blockIdx.x, tid = threadIdx.x;
    const int n = min(bcnt[b], BCAP);
    for (int i = tid; i < n; i += 1024) ent[i] = pairs[(size_t)b*BCAP + i];
    if (tid < 128) lh[tid] = 0;
    __syncthreads();
    for (int i = tid; i < n; i += 1024) atomicAdd(&lh[ent[i] >> 17], 1);
    __syncthreads();
    if (tid == 0) { int run = 0; for (int j = 0; j < 128; ++j) { ls[j] = run; run += lh[j]; } }
    __syncthreads();
    if (tid < 128) {
        int node = b*128 + tid;
        cnt[node]  = lh[tid];
        offs[node] = b*BCAP + ls[tid];
        lc[tid]    = ls[tid];
    }
    __syncthreads();
    for (int i = tid; i < n; i += 1024) {
        unsigned v = ent[i];
        int dl = (int)(v >> 17);
        int p = atomicAdd(&lc[dl], 1);
        pairs[(size_t)b*BCAP + p] = v & 0x1FFFFu;
    }
}

// ---------------- GAT aggregation: 8 lanes/node, shfl reduce, NO atomics ---
__global__ __launch_bounds__(256) void gat_agg8_k(
    const unsigned* __restrict__ pairs, const int* __restrict__ cnt,
    const int* __restrict__ offs,
    const float4* __restrict__ rows, const float* __restrict__ dval,
    const float* __restrict__ bias,
    float* __restrict__ out, bf* __restrict__ outb, int dotanh)
{
    int g = blockIdx.x*32 + (threadIdx.x >> 3);
    int l = threadIdx.x & 7;
    if (g >= NN) return;
    int beg = offs[g], m = cnt[g];
    float dv = dval[g];
    float acc[CC] = {};
    float den = 0.f;
    for (int i = l; i < m; i += 8) {
        unsigned s = pairs[beg + i];
        float4 r0 = rows[(size_t)s*2];
        float4 r1 = rows[(size_t)s*2+1];
        float e = r0.x + dv;
        e = e > 0.f ? e : 0.2f*e;
        float w = __expf(e);
        den += w;
        unsigned p01 = __float_as_uint(r0.y), p23 = __float_as_uint(r0.z);
        unsigned p45 = __float_as_uint(r0.w), p67 = __float_as_uint(r1.x);
        unsigned p89 = __float_as_uint(r1.y), pab = __float_as_uint(r1.z);
        acc[0]  += w*lo16(p01); acc[1]  += w*hi16(p01);
        acc[2]  += w*lo16(p23); acc[3]  += w*hi16(p23);
        acc[4]  += w*lo16(p45); acc[5]  += w*hi16(p45);
        acc[6]  += w*lo16(p67); acc[7]  += w*hi16(p67);
        acc[8]  += w*lo16(p89); acc[9]  += w*hi16(p89);
        acc[10] += w*lo16(pab); acc[11] += w*hi16(pab);
    }
#pragma unroll
    for (int off = 1; off < 8; off <<= 1) {
        den += __shfl_xor(den, off);
#pragma unroll
        for (int c = 0; c < CC; ++c) acc[c] += __shfl_xor(acc[c], off);
    }
    if (l == 0) {
        float inv = 1.f / den;
        float r[CC];
#pragma unroll
        for (int c = 0; c < CC; ++c) {
            r[c] = acc[c]*inv + bias[c];
            if (dotanh) r[c] = tanhf(r[c]);
        }
        if (out) {
            float4* orow = (float4*)(out + (size_t)g*CC);
            orow[0] = make_float4(r[0],r[1],r[2],r[3]);
            orow[1] = make_float4(r[4],r[5],r[6],r[7]);
            orow[2] = make_float4(r[8],r[9],r[10],r[11]);
        }
        if (outb) {
            s4v* brow = (s4v*)(outb + (size_t)g*CC);
            s4v b0, b1, b2;
            b0[0]=bfbits(r[0]); b0[1]=bfbits(r[1]); b0[2]=bfbits(r[2]); b0[3]=bfbits(r[3]);
            b1[0]=bfbits(r[4]); b1[1]=bfbits(r[5]); b1[2]=bfbits(r[6]); b1[3]=bfbits(r[7]);
            b2[0]=bfbits(r[8]); b2[1]=bfbits(r[9]); b2[2]=bfbits(r[10]); b2[3]=bfbits(r[11]);
            brow[0]=b0; brow[1]=b1; brow[2]=b2;
        }
    }
}

// ---------------- bf16 MFMA NT GEMM (LDS-swizzled, TBM in {64,128}) -------
template<int TBM>
__global__ __launch_bounds__(256) void gemm_bt(
    const bf* __restrict__ A, const bf* __restrict__ B,
    const float* __restrict__ bias, float* __restrict__ Cf, bf* __restrict__ Cb,
    int K, int lda, int ldb, int ldc,
    long long sA1, long long sA2, long long sB1, long long sB2,
    long long sC1, long long sC2, int bdiv, long long sBias,
    float scale, int relu, int vtmode)
{
    constexpr int MI = TBM/32;
    __shared__ bf As[TBM*32];
    __shared__ bf Bs[64*32];
    const int tid = threadIdx.x, lane = tid & 63, wave = tid >> 6;
    const int z = blockIdx.z, z1 = z / bdiv, z2 = z % bdiv;
    const bf* Ab = A + z1*sA1 + z2*sA2;
    const bf* Bb = B + z1*sB1 + z2*sB2;
    const int bm = blockIdx.y * TBM, bn = blockIdx.x * 64;
    const int l4 = lane >> 2;
    const int swz0 = (l4 >> 1) & 3;
    const int lc = (((lane & 3) ^ swz0) * 8);
    const int arow0 = wave*(TBM/4) + l4;
    const int brow  = wave*16 + l4;
    const int wm = wave >> 1, wn = wave & 1;
    const int fr = lane & 15;
    const int gsw = (((lane >> 4) ^ ((fr >> 1) & 3)) * 8);
    f4v acc[MI][2] = {};

    for (int k0 = 0; k0 < K; k0 += 32) {
        gl16(Ab + (size_t)(bm + arow0)*lda + k0 + lc, As + wave*(TBM/4)*32);
        if constexpr (TBM == 128)
            gl16(Ab + (size_t)(bm + arow0 + 16)*lda + k0 + lc, As + wave*1024 + 512);
        gl16(Bb + (size_t)(bn + brow )*ldb + k0 + lc, Bs + wave*512);
        __syncthreads();
        s8v af[MI], bfv[2];
#pragma unroll
        for (int mi = 0; mi < MI; ++mi)
            af[mi] = *(const s8v*)&As[(wm*(TBM/2) + mi*16 + fr)*32 + gsw];
#pragma unroll
        for (int nj = 0; nj < 2; ++nj)
            bfv[nj] = *(const s8v*)&Bs[(wn*32 + nj*16 + fr)*32 + gsw];
#pragma unroll
        for (int mi = 0; mi < MI; ++mi)
#pragma unroll
            for (int nj = 0; nj < 2; ++nj)
                acc[mi][nj] = __builtin_amdgcn_mfma_f32_16x16x32_bf16(
                    af[mi], bfv[nj], acc[mi][nj], 0, 0, 0);
        __syncthreads();
    }

    const float* bp = bias ? bias + z1*sBias : nullptr;
    if (vtmode && z1 == 2) {
        bf* vt = Cb + 2*sC1;
#pragma unroll
        for (int mi = 0; mi < MI; ++mi) {
#pragma unroll
            for (int nj = 0; nj < 2; ++nj) {
                int col = bn + wn*32 + nj*16 + fr;
                float bv = bp ? bp[col] : 0.f;
                int row0 = bm + wm*(TBM/2) + mi*16 + (lane>>4)*4;
                int b = row0 >> 9, s0 = row0 & 511;
                int h = col / HDI, dd = col - h*HDI;
                s4v pk;
#pragma unroll
                for (int r = 0; r < 4; ++r)
                    pk[r] = bfbits(acc[mi][nj][r] + bv);
                *(s4v*)&vt[((size_t)((b*HH + h)*HDI + dd))*SS + s0] = pk;
            }
        }
        return;
    }
    float* Cfb = Cf ? Cf + z1*sC1 + z2*sC2 : nullptr;
    bf*    Cbb = Cb ? Cb + z1*sC1 + z2*sC2 : nullptr;
#pragma unroll
    for (int mi = 0; mi < MI; ++mi) {
#pragma unroll
        for (int nj = 0; nj < 2; ++nj) {
            int col = bn + wn*32 + nj*16 + fr;
            float bv = bp ? bp[col] : 0.f;
#pragma unroll
            for (int r = 0; r < 4; ++r) {
                int row = bm + wm*(TBM/2) + mi*16 + (lane>>4)*4 + r;
                float vv = (acc[mi][nj][r] + bv) * scale;
                if (relu) vv = fmaxf(vv, 0.f);
                if (Cfb) Cfb[(size_t)row*ldc + col] = vv;
                if (Cbb) Cbb[(size_t)row*ldc + col] = __float2bfloat16(vv);
            }
        }
    }
}

// ---------------- fused QK^T + row-softmax -> P bf16 ----------------------
// grid (16 q-tiles, 12 bh). Per block: 32 q-rows x all 512 k-cols.
// Wave w owns cols [w*128, w*128+128). acc = 2 Mfrag x 8 Nfrag f4v.
__global__ __launch_bounds__(256) void qk_softmax_k(
    const bf* __restrict__ q, const bf* __restrict__ k, bf* __restrict__ P)
{
    __shared__ bf Qs[32*32];
    __shared__ bf Ks[512*32];
    __shared__ float redm[32][4];
    __shared__ float reds[32][4];
    const int tid = threadIdx.x, lane = tid & 63, wave = tid >> 6;
    const int bh = blockIdx.y;
    const int b = bh / HH, h = bh % HH;
    const int q0 = blockIdx.x * 32;
    const bf* Qp = q + (size_t)(b*SS + q0)*DD + h*HDI;
    const bf* Kp = k + (size_t)(b*SS)*DD + h*HDI;
    const int l4 = lane >> 2;
    const int swz0 = (l4 >> 1) & 3;
    const int lc = (((lane & 3) ^ swz0) * 8);
    const int fr = lane & 15, q4 = lane >> 4;
    const int gsw = ((q4 ^ ((fr >> 1) & 3)) * 8);
    f4v acc[2][8] = {};

    for (int k0 = 0; k0 < HDI; k0 += 32) {
        if (wave < 2)
            gl16(Qp + (size_t)(wave*16 + l4)*DD + k0 + lc, Qs + wave*512);
#pragma unroll
        for (int it = 0; it < 8; ++it) {
            int srow = it*64 + wave*16 + l4;
            gl16(Kp + (size_t)srow*DD + k0 + lc, Ks + (it*64 + wave*16)*32);
        }
        __syncthreads();
        s8v af[2], bfv[8];
#pragma unroll
        for (int mi = 0; mi < 2; ++mi)
            af[mi] = *(const s8v*)&Qs[(mi*16 + fr)*32 + gsw];
#pragma unroll
        for (int nj = 0; nj < 8; ++nj)
            bfv[nj] = *(const s8v*)&Ks[(wave*128 + nj*16 + fr)*32 + gsw];
#pragma unroll
        for (int mi = 0; mi < 2; ++mi)
#pragma unroll
            for (int nj = 0; nj < 8; ++nj)
                acc[mi][nj] = __builtin_amdgcn_mfma_f32_16x16x32_bf16(
                    af[mi], bfv[nj], acc[mi][nj], 0, 0, 0);
        __syncthreads();
    }

    // scale
#pragma unroll
    for (int mi = 0; mi < 2; ++mi)
#pragma unroll
        for (int nj = 0; nj < 8; ++nj)
            acc[mi][nj] *= ATT_SCALE;

    // row max: local over 8 nj, shfl over 16 col-lanes, LDS over 4 waves
    float mx[2][4];
#pragma unroll
    for (int mi = 0; mi < 2; ++mi)
#pragma unroll
        for (int r = 0; r < 4; ++r) {
            float m = acc[mi][0][r];
#pragma unroll
            for (int nj = 1; nj < 8; ++nj) m = fmaxf(m, acc[mi][nj][r]);
#pragma unroll
            for (int off = 1; off < 16; off <<= 1)
                m = fmaxf(m, __shfl_xor(m, off));
            if (fr == 0) redm[mi*16 + q4*4 + r][wave] = m;
            mx[mi][r] = m;
        }
    __syncthreads();
#pragma unroll
    for (int mi = 0; mi < 2; ++mi)
#pragma unroll
        for (int r = 0; r < 4; ++r) {
            int row = mi*16 + q4*4 + r;
            mx[mi][r] = fmaxf(fmaxf(redm[row][0], redm[row][1]),
                              fmaxf(redm[row][2], redm[row][3]));
        }
    // exp + row sum
    float sm[2][4];
#pragma unroll
    for (int mi = 0; mi < 2; ++mi)
#pragma unroll
        for (int r = 0; r < 4; ++r) {
            float s = 0.f;
#pragma unroll
            for (int nj = 0; nj < 8; ++nj) {
                float e = __expf(acc[mi][nj][r] - mx[mi][r]);
                acc[mi][nj][r] = e;
                s += e;
            }
#pragma unroll
            for (int off = 1; off < 16; off <<= 1)
                s += __shfl_xor(s, off);
            if (fr == 0) reds[mi*16 + q4*4 + r][wave] = s;
            sm[mi][r] = s;
        }
    __syncthreads();
    bf* Pp = P + (size_t)bh*SS*SS;
#pragma unroll
    for (int mi = 0; mi < 2; ++mi)
#pragma unroll
        for (int r = 0; r < 4; ++r) {
            int row = mi*16 + q4*4 + r;
            float tot = reds[row][0] + reds[row][1] + reds[row][2] + reds[row][3];
            float inv = 1.f / tot;
#pragma unroll
            for (int nj = 0; nj < 8; ++nj) {
                int col = wave*128 + nj*16 + fr;
                Pp[(size_t)(q0 + row)*SS + col] =
                    __float2bfloat16(acc[mi][nj][r] * inv);
            }
        }
}

// ---------------- direct conv GEMM, 64x64 tile, split-K -------------------
template<int CIN, int MODE>
__global__ __launch_bounds__(256) void conv_bt(
    const bf* __restrict__ A0, const bf* __restrict__ A1,
    const bf* __restrict__ Bw, float* __restrict__ Cpart,
    int K, int M, int N, int Lout, int Lin, int splitk)
{
    __shared__ bf As[64*32];
    __shared__ bf Bs[64*32];
    const int tid = threadIdx.x, lane = tid & 63, wave = tid >> 6;
    const int bm = blockIdx.y * 64, bn = blockIdx.x * 64;
    const int kchunk = K / splitk;
    const int kbeg = blockIdx.z * kchunk, kend = kbeg + kchunk;
    const int l4 = lane >> 2;
    const int swz0 = (l4 >> 1) & 3;
    const int lc = (((lane & 3) ^ swz0) * 8);
    const int arow = bm + wave*16 + l4;
    const int brow = bn + wave*16 + l4;
    const int ab = arow / Lout, al = arow % Lout;
    const int wm = wave >> 1, wn = wave & 1;
    const int fr = lane & 15;
    const int gsw = (((lane >> 4) ^ ((fr >> 1) & 3)) * 8);
    f4v acc[2][2] = {};

    for (int k0 = kbeg; k0 < kend; k0 += 32) {
        int kk  = k0 / CIN;
        int ci0 = k0 - kk*CIN;
        int row;
        if constexpr (MODE == 1)      row = 2*al + kk + 1;
        else if constexpr (MODE == 2) row = (al + kk + 1) >> 1;
        else                          row = al + kk;
        const bf* src;
        if constexpr (MODE == 3) {
            constexpr int CH = CIN/2;
            bool lohalf = ci0 < CH;
            src = (lohalf ? A0 : A1)
                + ((size_t)(ab*(Lin+2) + row))*CH + (lohalf ? ci0 : ci0 - CH);
        } else {
            src = A0 + ((size_t)(ab*(Lin+2) + row))*CIN + ci0;
        }
        gl16(src + lc, As + wave*512);
        gl16(Bw + (size_t)brow*K + k0 + lc, Bs + wave*512);
        __syncthreads();
        s8v af[2], bfv[2];
#pragma unroll
        for (int mi = 0; mi < 2; ++mi)
            af[mi] = *(const s8v*)&As[(wm*32 + mi*16 + fr)*32 + gsw];
#pragma unroll
        for (int nj = 0; nj < 2; ++nj)
            bfv[nj] = *(const s8v*)&Bs[(wn*32 + nj*16 + fr)*32 + gsw];
#pragma unroll
        for (int mi = 0; mi < 2; ++mi)
#pragma unroll
            for (int nj = 0; nj < 2; ++nj)
                acc[mi][nj] = __builtin_amdgcn_mfma_f32_16x16x32_bf16(
                    af[mi], bfv[nj], acc[mi][nj], 0, 0, 0);
        __syncthreads();
    }

    float* Cp = Cpart + (size_t)blockIdx.z * M * N;
#pragma unroll
    for (int mi = 0; mi < 2; ++mi)
#pragma unroll
        for (int nj = 0; nj < 2; ++nj) {
            int col = bn + wn*32 + nj*16 + fr;
#pragma unroll
            for (int r = 0; r < 4; ++r) {
                int row = bm + wm*32 + mi*16 + (lane>>4)*4 + r;
                Cp[(size_t)row*N + col] = acc[mi][nj][r];
            }
        }
}

// ---------------- conv epilogue: sum nsplit partials + bias (+relu) -------
__global__ __launch_bounds__(256) void convepi_k(
    const float* __restrict__ part, const float* __restrict__ bias,
    bf* __restrict__ outb, float* __restrict__ outf,
    int M, int N, int Lout, int relu, int nsplit)
{
    int total = M * (N >> 3);
    int i = blockIdx.x*256 + threadIdx.x;
    if (i >= total) return;
    int c8 = (i % (N >> 3)) * 8;
    int row = i / (N >> 3);
    float v[8];
#pragma unroll
    for (int j = 0; j < 8; ++j) v[j] = bias[c8+j];
    for (int z = 0; z < nsplit; ++z) {
        const float* p = part + (size_t)z*M*N + (size_t)row*N + c8;
#pragma unroll
        for (int j = 0; j < 8; ++j) v[j] += p[j];
    }
    if (relu) {
#pragma unroll
        for (int j = 0; j < 8; ++j) v[j] = fmaxf(v[j], 0.f);
    }
    if (outb) {
        int b = row / Lout, l = row % Lout;
        s8v pk;
#pragma unroll
        for (int j = 0; j < 8; ++j) pk[j] = bfbits(v[j]);
        *(s8v*)&outb[((size_t)(b*(Lout+2) + l + 1))*N + c8] = pk;
    }
    if (outf) {
        float4* o = (float4*)(outf + (size_t)row*N + c8);
        o[0] = make_float4(v[0],v[1],v[2],v[3]);
        o[1] = make_float4(v[4],v[5],v[6],v[7]);
    }
}

// ---------------- unified prep: casts + bias packs + pad-zeros ------------
struct PJob { int type; const float* src; void* dst; int a; int b; };
struct PJobs { PJob j[14]; };
__global__ __launch_bounds__(256) void prep_k(PJobs J)
{
    PJob jb = J.j[blockIdx.y];
    if (jb.type == 0) {
        for (int i = blockIdx.x*256 + threadIdx.x; i < jb.a; i += gridDim.x*256) {
            float4 v = ((const float4*)jb.src)[i];
            s4v p;
            p[0]=bfbits(v.x); p[1]=bfbits(v.y); p[2]=bfbits(v.z); p[3]=bfbits(v.w);
            ((s4v*)jb.dst)[i] = p;
        }
    } else if (jb.type == 1) {
        for (int i = blockIdx.x*256 + threadIdx.x; i < jb.a; i += gridDim.x*256)
            ((float4*)jb.dst)[i] = ((const float4*)jb.src)[i];
    } else {
        int n8 = BB * 2 * (jb.b >> 3);
        for (int i = blockIdx.x*256 + threadIdx.x; i < n8; i += gridDim.x*256) {
            int c8 = i % (jb.b >> 3); int r = i / (jb.b >> 3);
            int bb = r >> 1; int row = (r & 1) ? (jb.a + 1) : 0;
            s8v z = {0,0,0,0,0,0,0,0};
            *(s8v*)&((bf*)jb.dst)[((size_t)(bb*(jb.a+2) + row))*jb.b + c8*8] = z;
        }
    }
}

// ---------------- 5-job conv weight transpose -----------------------------
struct WJob { const float* w; bf* wT; int Cout; int Cin; };
struct WJobs { WJob j[5]; };
__global__ __launch_bounds__(256) void wtrans5_k(WJobs J)
{
    WJob jb = J.j[blockIdx.y];
    int n8 = jb.Cout * 3 * (jb.Cin >> 3);
    for (int i = blockIdx.x*256 + threadIdx.x; i < n8; i += gridDim.x*256) {
        int c8 = i % (jb.Cin >> 3); int r = i / (jb.Cin >> 3);
        int kk = r % 3; int co = r / 3;
        int ci = c8 * 8;
        s8v ov;
#pragma unroll
        for (int j = 0; j < 8; ++j)
            ov[j] = bfbits(jb.w[((size_t)co*jb.Cin + ci + j)*3 + kk]);
        *(s8v*)&jb.wT[(size_t)co*3*jb.Cin + (size_t)kk*jb.Cin + ci] = ov;
    }
}

// ---------------- layernorm over D=576 (ob optionally padded-layout) ------
__global__ __launch_bounds__(256) void ln_k(
    const float* __restrict__ a, const float* __restrict__ r,
    const float* __restrict__ g, const float* __restrict__ be,
    float* __restrict__ out, bf* __restrict__ ob, int padout)
{
    int row = blockIdx.x; int tid = threadIdx.x;
    __shared__ float red[256], red2[256];
    size_t base = (size_t)row * DD;
    size_t base2 = padout ? ((size_t)(row + 2*(row/SS) + 1))*DD : base;
    float x0 = a[base+tid]      + r[base+tid];
    float x1 = a[base+tid+256]  + r[base+tid+256];
    float x2 = (tid < 64) ? (a[base+tid+512] + r[base+tid+512]) : 0.f;
    float s  = x0+x1+x2;
    float s2 = x0*x0 + x1*x1 + x2*x2;
    red[tid] = s; red2[tid] = s2; __syncthreads();
    for (int off = 128; off > 0; off >>= 1) {
        if (tid < off) { red[tid] += red[tid+off]; red2[tid] += red2[tid+off]; }
        __syncthreads();
    }
    float mean = red[0] / (float)DD;
    float var  = red2[0] / (float)DD - mean*mean;
    float inv = rsqrtf(var + 1e-5f);
    float y0 = (x0-mean)*inv*g[tid]     + be[tid];
    float y1 = (x1-mean)*inv*g[tid+256] + be[tid+256];
    if (out) { out[base+tid] = y0; out[base+tid+256] = y1; }
    if (ob)  { ob[base2+tid] = __float2bfloat16(y0); ob[base2+tid+256] = __float2bfloat16(y1); }
    if (tid < 64) {
        float y2 = (x2-mean)*inv*g[tid+512] + be[tid+512];
        if (out) out[base+tid+512] = y2;
        if (ob)  ob[base2+tid+512] = __float2bfloat16(y2);
    }
}

// ---------------- launch ----------------
extern "C" void kernel_launch(void* const* d_in, const int* in_sizes, int n_in,
                              void* d_out, int out_size, void* d_ws, size_t ws_size,
                              hipStream_t stream)
{
    const int*   edge   = (const int*)  d_in[0];
    const float* x      = (const float*)d_in[1];
    const float* mask   = (const float*)d_in[2];
    const float* noise  = (const float*)d_in[3];
    const float* W_enc  = (const float*)d_in[4];
    const float* asrc_e = (const float*)d_in[5];
    const float* adst_e = (const float*)d_in[6];
    const float* b_enc  = (const float*)d_in[7];
    const float* Wq = (const float*)d_in[8];  const float* bq = (const float*)d_in[9];
    const float* Wk = (const float*)d_in[10]; const float* bk = (const float*)d_in[11];
    const float* Wv = (const float*)d_in[12]; const float* bv = (const float*)d_in[13];
    const float* Wo = (const float*)d_in[14]; const float* bo = (const float*)d_in[15];
    const float* ln1g = (const float*)d_in[16]; const float* ln1b = (const float*)d_in[17];
    const float* W1 = (const float*)d_in[18]; const float* b1 = (const float*)d_in[19];
    const float* W2 = (const float*)d_in[20]; const float* b2 = (const float*)d_in[21];
    const float* ln2g = (const float*)d_in[22]; const float* ln2b = (const float*)d_in[23];
    const float* enc1_w = (const float*)d_in[24]; const float* enc1_b = (const float*)d_in[25];
    const float* down_w = (const float*)d_in[26]; const float* down_b = (const float*)d_in[27];
    const float* bott_w = (const float*)d_in[28]; const float* bott_b = (const float*)d_in[29];
    const float* up_w   = (const float*)d_in[30]; const float* up_b   = (const float*)d_in[31];
    const float* dec_w  = (const float*)d_in[32]; const float* dec_b  = (const float*)d_in[33];
    const float* W_dec  = (const float*)d_in[34];
    const float* asrc_d = (const float*)d_in[35];
    const float* adst_d = (const float*)d_in[36];
    const float* b_dec  = (const float*)d_in[37];
    float* out = (float*)d_out;

    float* ws = (float*)d_ws;
    float4*   rows  = (float4*)ws;              // 786432 f
    float*    dval  = ws + 786432;              // 98304
    int*      cnt   = (int*)(ws + 884736);      // 98304
    int*      offs  = (int*)(ws + 983040);      // 98304
    unsigned* pairs = (unsigned*)(ws + 1376256);// 1966080 u32
    int*      bcnt  = (int*)(ws + 3342336);     // 1024
    float*    t     = ws + 3343360;             // 1179648
    bf*       tb    = (bf*)(ws + 4523008);      // 589824 f
    bf*       qb    = (bf*)(ws + 5112832);      // 589824 f
    bf*       kb    = (bf*)(ws + 5702656);      // 589824 f
    bf*       vb    = (bf*)(ws + 6292480);      // 589824 f (holds V TRANSPOSED)
    float*    big   = ws + 6882304;             // 4718592 f shared scratch
    int*      gcnt  = (int*)big;                // sort: 393216
    int*      gbase = (int*)(big + 393216);     // sort: 393216
    bf*       Pb    = (bf*)big;                 // attn: 1572864 f (after sort done)
    bf*       wTbott = (bf*)(big + 1572864);    // conv: 1990656 f
    float*    o     = ws + 11600896;            // 1179648
    float*    parts = ws + 11600896;            // conv: 4718592 f (o..ff1b dead)
    float*    t1    = ws + 12780544;            // 1179648
    bf*       t1b   = (bf*)(ws + 13960192);     // 589824 f
    bf*       ff1b  = (bf*)(ws + 14550016);     // 2097152 f
    bf*       t2p   = (bf*)(ws + 16647168);     // 592128 f  [4][514][576]
    bf*       e1p   = (bf*)(ws + 17239296);     // 592128 f
    bf*       d1p   = (bf*)(ws + 17831424);     // 594432 f  [4][258][1152]
    bf*       btbp  = (bf*)(ws + 18425856);     // 594432 f
    bf*       upp   = (bf*)(ws + 19020288);     // 592128 f
    float*    dec   = ws + 19612416;            // 1179648
    bf*       wTb   = (bf*)(ws + 20792064);     // 995328 f
    bf*       Wqb   = (bf*)(ws + 21787392);
    bf*       Wkb   = (bf*)(ws + 21953280);
    bf*       Wvb   = (bf*)(ws + 22119168);
    bf*       Wob   = (bf*)(ws + 22285056);
    bf*       W1b   = (bf*)(ws + 22450944);     // 589824
    bf*       W2b   = (bf*)(ws + 23040768);     // 589824
    float*    biasQKV = ws + 23630592;          // 1728
    bf*       vt    = vb;
    bf*       attnO = qb;
    bf*       wTenc  = wTb;
    bf*       wTdown = (bf*)t;                  // t dead after ln1
    bf*       wTup   = kb;                      // kb dead after qk_softmax
    bf*       wTdec  = tb;                      // tb dead after QKV

    const int* e0 = edge;
    const int* e1i = edge + EE;

    // ---- 0. atomic-free binning + in-place fine sort ----
    binA1_k<<<BINB2, 256, 0, stream>>>(e1i, gcnt);
    binscan_k<<<NB, BINB2, 0, stream>>>(gcnt, gbase, bcnt);
    binA2_k<<<BINB2, 256, 0, stream>>>(e0, e1i, gbase, pairs);
    binB_k<<<NB, 1024, 0, stream>>>(pairs, bcnt, cnt, offs);

    // ---- unified prep ----
    {
        PJobs J;
        J.j[0]  = { 0, Wq, Wqb, DD*DD/4, 0 };
        J.j[1]  = { 0, Wk, Wkb, DD*DD/4, 0 };
        J.j[2]  = { 0, Wv, Wvb, DD*DD/4, 0 };
        J.j[3]  = { 0, Wo, Wob, DD*DD/4, 0 };
        J.j[4]  = { 0, W1, W1b, FFD*DD/4, 0 };
        J.j[5]  = { 0, W2, W2b, FFD*DD/4, 0 };
        J.j[6]  = { 1, bq, biasQKV,        DD/4, 0 };
        J.j[7]  = { 1, bk, biasQKV + DD,   DD/4, 0 };
        J.j[8]  = { 1, bv, biasQKV + 2*DD, DD/4, 0 };
        J.j[9]  = { 2, nullptr, t2p,  512, 576 };
        J.j[10] = { 2, nullptr, e1p,  512, 576 };
        J.j[11] = { 2, nullptr, d1p,  256, 1152 };
        J.j[12] = { 2, nullptr, btbp, 256, 1152 };
        J.j[13] = { 2, nullptr, upp,  512, 576 };
        prep_k<<<dim3(576, 14), 256, 0, stream>>>(J);
    }

    // ---- 1. GAT encoder ----
    gat_node_k<<<NN/256, 256, 0, stream>>>(x, mask, noise, W_enc, asrc_e, adst_e,
                                           rows, dval, 1);
    gat_agg8_k<<<NN/32, 256, 0, stream>>>(pairs, cnt, offs, rows, dval, b_enc,
                                          t, tb, 0);

    // ---- 2. transformer layer ----
    gemm_bt<128><<<dim3(9,16,3), 256, 0, stream>>>(tb, Wqb, biasQKV, nullptr, qb,
        DD, DD, DD, DD,
        0,0, (long long)DD*DD,0, (long long)MR*DD,0, 1, DD, 1.f, 0, 1);
    qk_softmax_k<<<dim3(16,12), 256, 0, stream>>>(qb, kb, Pb);
    gemm_bt<64><<<dim3(3,8,12), 256, 0, stream>>>(Pb, vt, nullptr, nullptr, attnO,
        SS, SS, SS, DD,
        3LL*SS*SS, (long long)SS*SS, 3LL*HDI*SS, (long long)HDI*SS,
        (long long)SS*DD, HDI, HH, 0, 1.f, 0, 0);
    gemm_bt<64><<<dim3(9,32,1), 256, 0, stream>>>(attnO, Wob, bo, o, nullptr,
        DD, DD, DD, DD, 0,0,0,0,0,0, 1, 0, 1.f, 0, 0);
    ln_k<<<MR, 256, 0, stream>>>(t, o, ln1g, ln1b, t1, t1b, 0);
    gemm_bt<128><<<dim3(32,16,1), 256, 0, stream>>>(t1b, W1b, b1, nullptr, ff1b,
        DD, DD, DD, FFD, 0,0,0,0,0,0, 1, 0, 1.f, 1, 0);
    gemm_bt<64><<<dim3(9,32,1), 256, 0, stream>>>(ff1b, W2b, b2, o, nullptr,
        FFD, FFD, FFD, DD, 0,0,0,0,0,0, 1, 0, 1.f, 0, 0);
    ln_k<<<MR, 256, 0, stream>>>(t1, o, ln2g, ln2b, nullptr, t2p, 1);

    // ---- 3. UNet1d ----
    {
        WJobs W5;
        W5.j[0] = { enc1_w, wTenc,  576,  576 };
        W5.j[1] = { down_w, wTdown, 1152, 576 };
        W5.j[2] = { bott_w, wTbott, 1152, 1152 };
        W5.j[3] = { up_w,   wTup,   576,  1152 };
        W5.j[4] = { dec_w,  wTdec,  576,  1152 };
        wtrans5_k<<<dim3(1024, 5), 256, 0, stream>>>(W5);
    }
    conv_bt<576,0><<<dim3(9,32,3), 256, 0, stream>>>(t2p, nullptr, wTenc, parts,
        1728, 2048, 576, 512, 512, 3);
    convepi_k<<<576, 256, 0, stream>>>(parts, enc1_b, e1p, nullptr, 2048, 576, 512, 1, 3);
    conv_bt<576,1><<<dim3(18,16,3), 256, 0, stream>>>(e1p, nullptr, wTdown, parts,
        1728, 1024, 1152, 256, 512, 3);
    convepi_k<<<576, 256, 0, stream>>>(parts, down_b, d1p, nullptr, 1024, 1152, 256, 1, 3);
    conv_bt<1152,0><<<dim3(18,16,4), 256, 0, stream>>>(d1p, nullptr, wTbott, parts,
        3456, 1024, 1152, 256, 256, 4);
    convepi_k<<<576, 256, 0, stream>>>(parts, bott_b, btbp, nullptr, 1024, 1152, 256, 1, 4);
    conv_bt<1152,2><<<dim3(9,32,4), 256, 0, stream>>>(btbp, nullptr, wTup, parts,
        3456, 2048, 576, 512, 256, 4);
    convepi_k<<<576, 256, 0, stream>>>(parts, up_b, upp, nullptr, 2048, 576, 512, 1, 4);
    conv_bt<1152,3><<<dim3(9,32,4), 256, 0, stream>>>(upp, e1p, wTdec, parts,
        3456, 2048, 576, 512, 512, 4);
    convepi_k<<<576, 256, 0, stream>>>(parts, dec_b, nullptr, dec, 2048, 576, 512, 0, 4);

    // ---- 4. GAT decoder + tanh ----
    gat_node_k<<<NN/256, 256, 0, stream>>>(dec, nullptr, nullptr, W_dec, asrc_d, adst_d,
                                           rows, dval, 0);
    gat_agg8_k<<<NN/32, 256, 0, stream>>>(pairs, cnt, offs, rows, dval, b_dec,
                                          out, nullptr, 1);
}